// Round 2
// baseline (2366.385 us; speedup 1.0000x reference)
//
#include <hip/hip_runtime.h>
#include <hip/hip_bf16.h>

// ---------------------------------------------------------------------------
// GIN: 3x (segment-sum aggregate -> Linear -> BN -> ReLU -> Linear -> ReLU)
//      -> concat -> Linear(768,768)+ReLU -> Linear(768,2) -> (h, softmax)
// fp32 implementation, CSR-based aggregation, tiled fp32 GEMM.
// ---------------------------------------------------------------------------

#define GIN_N_FEAT_IN 128
#define GIN_H 256

// ---------------- CSR build ----------------

__global__ void count_kernel(const int* __restrict__ ei, int* __restrict__ deg, int E) {
    for (int e = blockIdx.x * blockDim.x + threadIdx.x; e < E; e += gridDim.x * blockDim.x) {
        atomicAdd(&deg[ei[E + e]], 1);   // dst = ei[1][e]
    }
}

__global__ void scan_kernel(const int* __restrict__ deg, int* __restrict__ row_start, int N) {
    __shared__ int sm[256];
    __shared__ int base_s;
    int tid = threadIdx.x;
    if (tid == 0) base_s = 0;
    __syncthreads();
    for (int start = 0; start < N; start += 256) {
        int idx = start + tid;
        int v = (idx < N) ? deg[idx] : 0;
        sm[tid] = v;
        __syncthreads();
        #pragma unroll
        for (int off = 1; off < 256; off <<= 1) {
            int t = (tid >= off) ? sm[tid - off] : 0;
            __syncthreads();
            sm[tid] += t;
            __syncthreads();
        }
        int incl = sm[tid];
        if (idx < N) row_start[idx] = base_s + incl - v;   // exclusive
        __syncthreads();
        if (tid == 255) base_s += incl;                    // incl == chunk total for tid 255
        __syncthreads();
    }
    if (tid == 0) row_start[N] = base_s;
}

__global__ void scatter_kernel(const int* __restrict__ ei, int* __restrict__ cursor,
                               int* __restrict__ perm, int E) {
    for (int e = blockIdx.x * blockDim.x + threadIdx.x; e < E; e += gridDim.x * blockDim.x) {
        int d = ei[E + e];
        int pos = atomicAdd(&cursor[d], 1);
        perm[pos] = ei[e];                                  // src = ei[0][e]
    }
}

// ---------------- aggregation: hpre[i] = x[i] + sum_{j in N(i)} x[j] ----------------

__global__ void agg_kernel(const float* __restrict__ xsrc, int stride, int width,
                           const int* __restrict__ row_start,
                           const int* __restrict__ perm,
                           float* __restrict__ hpre) {
    int i = blockIdx.x;
    int f = threadIdx.x;
    if (f >= width) return;
    int s = row_start[i], e = row_start[i + 1];
    float acc = xsrc[(size_t)i * stride + f];
    for (int j = s; j < e; ++j) {
        int sn = perm[j];
        acc += xsrc[(size_t)sn * stride + f];
    }
    hpre[(size_t)i * width + f] = acc;
}

// ---------------- tiled fp32 GEMM: C[M x Nc] = A[M x K] * B[K x Nc] (+bias)(+relu) --------
// grid.x = Nc/64 tiles, grid.y = ceil(M/64). 256 threads, 4x4 microtile.

template <bool RELU, bool BIAS>
__global__ __launch_bounds__(256) void gemm_f32(
    const float* __restrict__ A, int lda,
    const float* __restrict__ B, int ldb,
    const float* __restrict__ bias,
    float* __restrict__ C, int ldc,
    int M, int K) {
    __shared__ float As[16][64];
    __shared__ float Bs[16][64];
    const int tid = threadIdx.x;
    const int bm = blockIdx.y * 64;
    const int bn = blockIdx.x * 64;
    const int tx = tid & 15, ty = tid >> 4;
    const int arow = tid >> 2, acol = (tid & 3) * 4;
    const int brow = tid >> 4, bcol = (tid & 15) * 4;
    const bool aval = (bm + arow) < M;

    float acc[4][4] = {};

    for (int k0 = 0; k0 < K; k0 += 16) {
        float4 av = make_float4(0.f, 0.f, 0.f, 0.f);
        if (aval) av = *(const float4*)(A + (size_t)(bm + arow) * lda + k0 + acol);
        float4 bv = *(const float4*)(B + (size_t)(k0 + brow) * ldb + bn + bcol);
        __syncthreads();
        As[acol + 0][arow] = av.x;
        As[acol + 1][arow] = av.y;
        As[acol + 2][arow] = av.z;
        As[acol + 3][arow] = av.w;
        *(float4*)&Bs[brow][bcol] = bv;
        __syncthreads();
        #pragma unroll
        for (int k = 0; k < 16; ++k) {
            float a0 = As[k][ty * 4 + 0];
            float a1 = As[k][ty * 4 + 1];
            float a2 = As[k][ty * 4 + 2];
            float a3 = As[k][ty * 4 + 3];
            float4 b = *(float4*)&Bs[k][tx * 4];
            acc[0][0] = fmaf(a0, b.x, acc[0][0]); acc[0][1] = fmaf(a0, b.y, acc[0][1]);
            acc[0][2] = fmaf(a0, b.z, acc[0][2]); acc[0][3] = fmaf(a0, b.w, acc[0][3]);
            acc[1][0] = fmaf(a1, b.x, acc[1][0]); acc[1][1] = fmaf(a1, b.y, acc[1][1]);
            acc[1][2] = fmaf(a1, b.z, acc[1][2]); acc[1][3] = fmaf(a1, b.w, acc[1][3]);
            acc[2][0] = fmaf(a2, b.x, acc[2][0]); acc[2][1] = fmaf(a2, b.y, acc[2][1]);
            acc[2][2] = fmaf(a2, b.z, acc[2][2]); acc[2][3] = fmaf(a2, b.w, acc[2][3]);
            acc[3][0] = fmaf(a3, b.x, acc[3][0]); acc[3][1] = fmaf(a3, b.y, acc[3][1]);
            acc[3][2] = fmaf(a3, b.z, acc[3][2]); acc[3][3] = fmaf(a3, b.w, acc[3][3]);
        }
    }

    float4 bb = make_float4(0.f, 0.f, 0.f, 0.f);
    if (BIAS) bb = *(const float4*)(bias + bn + tx * 4);
    #pragma unroll
    for (int i = 0; i < 4; ++i) {
        int r = bm + ty * 4 + i;
        if (r < M) {
            float4 v;
            v.x = acc[i][0] + bb.x; v.y = acc[i][1] + bb.y;
            v.z = acc[i][2] + bb.z; v.w = acc[i][3] + bb.w;
            if (RELU) {
                v.x = fmaxf(v.x, 0.f); v.y = fmaxf(v.y, 0.f);
                v.z = fmaxf(v.z, 0.f); v.w = fmaxf(v.w, 0.f);
            }
            *(float4*)(C + (size_t)r * ldc + bn + tx * 4) = v;
        }
    }
}

// ---------------- BatchNorm (training stats over N) ----------------

__global__ void bn_stats(const float* __restrict__ h, float* __restrict__ sums, int Nrows) {
    int col = threadIdx.x;   // 256 threads = 256 cols
    float s = 0.f, s2 = 0.f;
    for (int r = blockIdx.x; r < Nrows; r += gridDim.x) {
        float v = h[(size_t)r * 256 + col];
        s += v; s2 += v * v;
    }
    atomicAdd(&sums[col], s);
    atomicAdd(&sums[256 + col], s2);
}

__global__ void bn_apply(float* __restrict__ h, const float* __restrict__ sums,
                         const float* __restrict__ g, const float* __restrict__ be, int Nrows) {
    int total = Nrows * 256;
    float inv = 1.0f / (float)Nrows;
    for (int idx = blockIdx.x * blockDim.x + threadIdx.x; idx < total;
         idx += gridDim.x * blockDim.x) {
        int col = idx & 255;
        float mu = sums[col] * inv;
        float var = sums[256 + col] * inv - mu * mu;
        float v = (h[idx] - mu) * rsqrtf(var + 1e-5f) * g[col] + be[col];
        h[idx] = fmaxf(v, 0.f);
    }
}

// ---------------- head: out_acc[i][j] += sum_k relu_chunk[i][k] * W2c[k][j] ----------------
// one wave per node; lane l covers k = 4l..4l+3 of the 256-wide chunk.

__global__ void head_dot(const float* __restrict__ tchunk, const float* __restrict__ W2c,
                         float* __restrict__ acc, int Nrows) {
    int wv = threadIdx.x >> 6;
    int lane = threadIdx.x & 63;
    int node = blockIdx.x * (blockDim.x >> 6) + wv;
    if (node >= Nrows) return;
    float4 xv = *(const float4*)(tchunk + (size_t)node * 256 + lane * 4);
    float4 w01 = *(const float4*)(W2c + lane * 8);       // rows 4l,4l+1 x 2 cols
    float4 w23 = *(const float4*)(W2c + lane * 8 + 4);   // rows 4l+2,4l+3 x 2 cols
    float o0 = xv.x * w01.x + xv.y * w01.z + xv.z * w23.x + xv.w * w23.z;
    float o1 = xv.x * w01.y + xv.y * w01.w + xv.z * w23.y + xv.w * w23.w;
    #pragma unroll
    for (int off = 32; off > 0; off >>= 1) {
        o0 += __shfl_down(o0, off);
        o1 += __shfl_down(o1, off);
    }
    if (lane == 0) {
        acc[(size_t)node * 2 + 0] += o0;
        acc[(size_t)node * 2 + 1] += o1;
    }
}

__global__ void finalize(const float* __restrict__ acc, const float* __restrict__ b2,
                         float* __restrict__ out, int Nrows) {
    int i = blockIdx.x * blockDim.x + threadIdx.x;
    if (i >= Nrows) return;
    float h0 = acc[2 * i] + b2[0];
    float h1 = acc[2 * i + 1] + b2[1];
    out[2 * i] = h0;
    out[2 * i + 1] = h1;
    float m = fmaxf(h0, h1);
    float e0 = expf(h0 - m), e1 = expf(h1 - m);
    float s = e0 + e1;
    out[(size_t)2 * Nrows + 2 * i] = e0 / s;
    out[(size_t)2 * Nrows + 2 * i + 1] = e1 / s;
}

// ---------------------------------------------------------------------------

extern "C" void kernel_launch(void* const* d_in, const int* in_sizes, int n_in,
                              void* d_out, int out_size, void* d_ws, size_t ws_size,
                              hipStream_t stream) {
    const int N = in_sizes[0] / GIN_N_FEAT_IN;     // 50000
    const int E = in_sizes[1] / 2;                 // 800000

    const float* x  = (const float*)d_in[0];
    const int*   ei = (const int*)d_in[1];
    // conv params: [W1, b1, g, be, W2, b2] starting at idx 2, 8, 14
    const float* cW1[3] = {(const float*)d_in[2],  (const float*)d_in[8],  (const float*)d_in[14]};
    const float* cb1[3] = {(const float*)d_in[3],  (const float*)d_in[9],  (const float*)d_in[15]};
    const float* cg [3] = {(const float*)d_in[4],  (const float*)d_in[10], (const float*)d_in[16]};
    const float* cbe[3] = {(const float*)d_in[5],  (const float*)d_in[11], (const float*)d_in[17]};
    const float* cW2[3] = {(const float*)d_in[6],  (const float*)d_in[12], (const float*)d_in[18]};
    const float* cb2[3] = {(const float*)d_in[7],  (const float*)d_in[13], (const float*)d_in[19]};
    const float* lin1_W = (const float*)d_in[20];  // [768,768]
    const float* lin1_b = (const float*)d_in[21];  // [768]
    const float* lin2_W = (const float*)d_in[22];  // [768,2]
    const float* lin2_b = (const float*)d_in[23];  // [2]
    float* out = (float*)d_out;

    // ---- workspace carve-up ----
    char* ws = (char*)d_ws;
    size_t off = 0;
    auto carve = [&](size_t bytes) {
        void* p = ws + off;
        off += (bytes + 255) & ~(size_t)255;
        return p;
    };
    float* Hcat    = (float*)carve((size_t)N * 768 * 4);   // h1|h2|h3 columns
    float* hpre    = (float*)carve((size_t)N * 256 * 4);
    float* hlin    = (float*)carve((size_t)N * 256 * 4);
    int*   row_st  = (int*)carve((size_t)(N + 1) * 4);
    int*   cursor  = (int*)carve((size_t)N * 4);
    int*   perm    = (int*)carve((size_t)E * 4);
    float* bnsums  = (float*)carve(512 * 4);
    float* out_acc = (float*)carve((size_t)N * 2 * 4);
    (void)ws_size;

    // ---- CSR build (per call; ws is re-poisoned) ----
    hipMemsetAsync(cursor, 0, (size_t)N * 4, stream);
    count_kernel<<<1024, 256, 0, stream>>>(ei, cursor, E);
    scan_kernel<<<1, 256, 0, stream>>>(cursor, row_st, N);
    hipMemcpyAsync(cursor, row_st, (size_t)N * 4, hipMemcpyDeviceToDevice, stream);
    scatter_kernel<<<1024, 256, 0, stream>>>(ei, cursor, perm, E);

    const int Mtiles = (N + 63) / 64;

    // ---- 3 GIN conv layers ----
    for (int L = 0; L < 3; ++L) {
        const float* src_x = (L == 0) ? x : (Hcat + (size_t)(L - 1) * 256);
        int stride = (L == 0) ? GIN_N_FEAT_IN : 768;
        int width  = (L == 0) ? GIN_N_FEAT_IN : 256;

        agg_kernel<<<N, width, 0, stream>>>(src_x, stride, width, row_st, perm, hpre);

        // GEMM1: hpre[N x width] * W1[width x 256] + b1 -> hlin
        gemm_f32<false, true><<<dim3(4, Mtiles), 256, 0, stream>>>(
            hpre, width, cW1[L], 256, cb1[L], hlin, 256, N, width);

        // BN (training stats) + ReLU in place
        hipMemsetAsync(bnsums, 0, 512 * 4, stream);
        bn_stats<<<256, 256, 0, stream>>>(hlin, bnsums, N);
        bn_apply<<<2048, 256, 0, stream>>>(hlin, bnsums, cg[L], cbe[L], N);

        // GEMM2: hlin[N x 256] * W2[256 x 256] + b2, ReLU -> Hcat column block L
        gemm_f32<true, true><<<dim3(4, Mtiles), 256, 0, stream>>>(
            hlin, 256, cW2[L], 256, cb2[L], Hcat + (size_t)L * 256, 768, N, 256);
    }

    // ---- head: chunked lin1 (768 -> 3 x 256) fused into lin2 accumulation ----
    hipMemsetAsync(out_acc, 0, (size_t)N * 2 * 4, stream);
    for (int c = 0; c < 3; ++c) {
        gemm_f32<true, true><<<dim3(4, Mtiles), 256, 0, stream>>>(
            Hcat, 768, lin1_W + (size_t)c * 256, 768, lin1_b + (size_t)c * 256,
            hlin, 256, N, 768);
        head_dot<<<(N + 3) / 4, 256, 0, stream>>>(hlin, lin2_W + (size_t)c * 512, out_acc, N);
    }
    finalize<<<(N + 255) / 256, 256, 0, stream>>>(out_acc, lin2_b, out, N);
}

// Round 3
// 1186.207 us; speedup vs baseline: 1.9949x; 1.9949x over previous
//
#include <hip/hip_runtime.h>
#include <hip/hip_bf16.h>

// ---------------------------------------------------------------------------
// GIN on MI355X: bf16 MFMA GEMMs (m97 structure: 128x128 tile, BK=32,
// global_load_lds width-16, B^T operand), f32 BN stats, CSR aggregation.
// ---------------------------------------------------------------------------

#define GIN_N_FEAT_IN 128
#define GIN_H 256
#define M_PAD_ROWS 50048   // 50000 padded to 128

typedef short short8 __attribute__((ext_vector_type(8)));
typedef float f32x4 __attribute__((ext_vector_type(4)));

__device__ inline ushort f32_to_bf16(float f) {
    union { float f; uint u; } x; x.f = f;
    uint r = x.u + 0x7fff + ((x.u >> 16) & 1);
    return (ushort)(r >> 16);
}
__device__ inline float bf16_to_f32(uint h) {
    union { uint u; float f; } x; x.u = h << 16;
    return x.f;
}
__device__ inline uint pack_bf16(float lo, float hi) {
    return (uint)f32_to_bf16(lo) | ((uint)f32_to_bf16(hi) << 16);
}

__device__ inline void gload_lds16(const ushort* g, ushort* l) {
    __builtin_amdgcn_global_load_lds(
        (const __attribute__((address_space(1))) void*)g,
        (__attribute__((address_space(3))) void*)l, 16, 0, 0);
}

// ---------------- conversions ----------------

__global__ void cvt_f32_bf16(const float* __restrict__ in, ushort* __restrict__ out, int npairs) {
    for (int i = blockIdx.x * blockDim.x + threadIdx.x; i < npairs; i += gridDim.x * blockDim.x) {
        float2 v = ((const float2*)in)[i];
        ((uint*)out)[i] = pack_bf16(v.x, v.y);
    }
}

// out[c][r] = bf16(in[r][c]);  in is [R][C] row-major
__global__ void transpose_cvt(const float* __restrict__ in, ushort* __restrict__ out, int R, int C) {
    int idx = blockIdx.x * blockDim.x + threadIdx.x;
    if (idx >= R * C) return;
    int r = idx / C, c = idx - r * C;
    out[(size_t)c * R + r] = f32_to_bf16(in[idx]);
}

// ---------------- CSR build ----------------

__global__ void count_kernel(const int* __restrict__ ei, int* __restrict__ deg, int E) {
    for (int e = blockIdx.x * blockDim.x + threadIdx.x; e < E; e += gridDim.x * blockDim.x) {
        atomicAdd(&deg[ei[E + e]], 1);   // dst = ei[1][e]
    }
}

__global__ void scan_kernel(const int* __restrict__ deg, int* __restrict__ row_start, int N) {
    __shared__ int sm[256];
    __shared__ int base_s;
    int tid = threadIdx.x;
    if (tid == 0) base_s = 0;
    __syncthreads();
    for (int start = 0; start < N; start += 256) {
        int idx = start + tid;
        int v = (idx < N) ? deg[idx] : 0;
        sm[tid] = v;
        __syncthreads();
        #pragma unroll
        for (int off = 1; off < 256; off <<= 1) {
            int t = (tid >= off) ? sm[tid - off] : 0;
            __syncthreads();
            sm[tid] += t;
            __syncthreads();
        }
        int incl = sm[tid];
        if (idx < N) row_start[idx] = base_s + incl - v;   // exclusive
        __syncthreads();
        if (tid == 255) base_s += incl;
        __syncthreads();
    }
    if (tid == 0) row_start[N] = base_s;
}

__global__ void scatter_kernel(const int* __restrict__ ei, int* __restrict__ cursor,
                               int* __restrict__ perm, int E) {
    for (int e = blockIdx.x * blockDim.x + threadIdx.x; e < E; e += gridDim.x * blockDim.x) {
        int d = ei[E + e];
        int pos = atomicAdd(&cursor[d], 1);
        perm[pos] = ei[e];                                  // src = ei[0][e]
    }
}

// ---------------- aggregation (bf16 in/out, f32 accumulate) ----------------
// hpre[i] = x[i] + sum_{j in N(i)} x[j].  blockDim = width/2, thread f -> cols 2f,2f+1.

__global__ void agg_bf16(const ushort* __restrict__ xsrc, int stride, int width,
                         const int* __restrict__ row_start, const int* __restrict__ perm,
                         ushort* __restrict__ out) {
    int i = blockIdx.x;
    int f = threadIdx.x;
    int s = row_start[i], e = row_start[i + 1];
    uint v = *(const uint*)(xsrc + (size_t)i * stride + 2 * f);
    float lo = bf16_to_f32(v & 0xffffu), hi = bf16_to_f32(v >> 16);
    for (int j = s; j < e; ++j) {
        int sn = perm[j];
        uint w = *(const uint*)(xsrc + (size_t)sn * stride + 2 * f);
        lo += bf16_to_f32(w & 0xffffu);
        hi += bf16_to_f32(w >> 16);
    }
    *(uint*)(out + (size_t)i * width + 2 * f) = pack_bf16(lo, hi);
}

// ---------------- bf16 MFMA GEMM (m97 structure) ----------------
// C[M_PAD x 256] = A[M_PAD x K](bf16,row-major) * Bt[256 x K](bf16,row-major)^T
// tile 128x128, BK=32, 256 threads = 4 waves in 2x2, each wave 64x64 (4x4 frags).
// grid = (2, M_PAD/128). No M guard: all row buffers padded to M_PAD_ROWS.

template <bool RELU, bool OUT_BF16>
__global__ __launch_bounds__(256) void gemm_mfma(
    const ushort* __restrict__ A, const ushort* __restrict__ Bt,
    const float* __restrict__ bias, void* __restrict__ Cout,
    int ldc, int K) {
    __shared__ ushort As[128 * 32];
    __shared__ ushort Bs[128 * 32];
    const int tid = threadIdx.x;
    const int bm = blockIdx.y * 128;
    const int bn = blockIdx.x * 128;
    const int lane = tid & 63;
    const int wid = tid >> 6;
    const int wr = wid >> 1, wc = wid & 1;

    f32x4 acc[4][4] = {};

    // staging: pass p covers rows/cols p*64 + tid/4, k-chunk (tid&3)*8 (16B)
    const int srow = tid >> 2;
    const int skcol = (tid & 3) * 8;
    const ushort* Ag0 = A + (size_t)(bm + srow) * K + skcol;
    const ushort* Ag1 = A + (size_t)(bm + 64 + srow) * K + skcol;
    const ushort* Bg0 = Bt + (size_t)(bn + srow) * K + skcol;
    const ushort* Bg1 = Bt + (size_t)(bn + 64 + srow) * K + skcol;
    ushort* As0 = &As[(tid & ~63) * 8];          // wave-uniform base, HW adds lane*16B
    ushort* As1 = &As[2048 + (tid & ~63) * 8];
    ushort* Bs0 = &Bs[(tid & ~63) * 8];
    ushort* Bs1 = &Bs[2048 + (tid & ~63) * 8];

    const int kk = (lane >> 4) * 8;      // k-offset of this lane's fragment
    const int fr = lane & 15;            // row (A) / col (B) within fragment

    for (int k0 = 0; k0 < K; k0 += 32) {
        gload_lds16(Ag0 + k0, As0);
        gload_lds16(Ag1 + k0, As1);
        gload_lds16(Bg0 + k0, Bs0);
        gload_lds16(Bg1 + k0, Bs1);
        __syncthreads();   // compiler emits vmcnt(0) drain before barrier
        short8 af[4], bf[4];
        #pragma unroll
        for (int m = 0; m < 4; ++m)
            af[m] = *(const short8*)&As[(wr * 64 + m * 16 + fr) * 32 + kk];
        #pragma unroll
        for (int n = 0; n < 4; ++n)
            bf[n] = *(const short8*)&Bs[(wc * 64 + n * 16 + fr) * 32 + kk];
        #pragma unroll
        for (int m = 0; m < 4; ++m)
            #pragma unroll
            for (int n = 0; n < 4; ++n)
                acc[m][n] = __builtin_amdgcn_mfma_f32_16x16x32_bf16(af[m], bf[n], acc[m][n], 0, 0, 0);
        __syncthreads();
    }

    // epilogue: C/D layout col=lane&15, row=(lane>>4)*4+reg  [m89/m91 verified]
    #pragma unroll
    for (int n = 0; n < 4; ++n) {
        const int col = bn + wc * 64 + n * 16 + fr;
        const float bv = bias[col];
        #pragma unroll
        for (int m = 0; m < 4; ++m) {
            const int row0 = bm + wr * 64 + m * 16 + (lane >> 4) * 4;
            #pragma unroll
            for (int r = 0; r < 4; ++r) {
                float v = acc[m][n][r] + bv;
                if (RELU) v = fmaxf(v, 0.f);
                if (OUT_BF16)
                    ((ushort*)Cout)[(size_t)(row0 + r) * ldc + col] = f32_to_bf16(v);
                else
                    ((float*)Cout)[(size_t)(row0 + r) * ldc + col] = v;
            }
        }
    }
}

// ---------------- BatchNorm (training stats over N) ----------------

__global__ void bn_stats(const float* __restrict__ h, float* __restrict__ sums, int Nrows) {
    int col = threadIdx.x;   // 256 threads = 256 cols
    float s = 0.f, s2 = 0.f;
    for (int r = blockIdx.x; r < Nrows; r += gridDim.x) {
        float v = h[(size_t)r * 256 + col];
        s += v; s2 += v * v;
    }
    atomicAdd(&sums[col], s);
    atomicAdd(&sums[256 + col], s2);
}

// normalize + relu, write bf16 (2 cols/thread)
__global__ void bn_apply(const float* __restrict__ h, const float* __restrict__ sums,
                         const float* __restrict__ g, const float* __restrict__ be,
                         ushort* __restrict__ outb, int Nrows) {
    int total = Nrows * 128;
    float inv = 1.0f / (float)Nrows;
    for (int idx = blockIdx.x * blockDim.x + threadIdx.x; idx < total;
         idx += gridDim.x * blockDim.x) {
        int row = idx >> 7;
        int cp = (idx & 127) * 2;
        float2 v = *(const float2*)(h + (size_t)row * 256 + cp);
        float mu0 = sums[cp] * inv,     mu1 = sums[cp + 1] * inv;
        float va0 = sums[256 + cp] * inv - mu0 * mu0;
        float va1 = sums[257 + cp] * inv - mu1 * mu1;
        float o0 = fmaxf((v.x - mu0) * rsqrtf(va0 + 1e-5f) * g[cp]     + be[cp],     0.f);
        float o1 = fmaxf((v.y - mu1) * rsqrtf(va1 + 1e-5f) * g[cp + 1] + be[cp + 1], 0.f);
        *(uint*)(outb + (size_t)row * 256 + cp) = pack_bf16(o0, o1);
    }
}

// ---------------- head ----------------

__global__ void head_dot(const float* __restrict__ tchunk, const float* __restrict__ W2c,
                         float* __restrict__ acc, int Nrows) {
    int wv = threadIdx.x >> 6;
    int lane = threadIdx.x & 63;
    int node = blockIdx.x * (blockDim.x >> 6) + wv;
    if (node >= Nrows) return;
    float4 xv = *(const float4*)(tchunk + (size_t)node * 256 + lane * 4);
    float4 w01 = *(const float4*)(W2c + lane * 8);
    float4 w23 = *(const float4*)(W2c + lane * 8 + 4);
    float o0 = xv.x * w01.x + xv.y * w01.z + xv.z * w23.x + xv.w * w23.z;
    float o1 = xv.x * w01.y + xv.y * w01.w + xv.z * w23.y + xv.w * w23.w;
    #pragma unroll
    for (int off = 32; off > 0; off >>= 1) {
        o0 += __shfl_down(o0, off);
        o1 += __shfl_down(o1, off);
    }
    if (lane == 0) {
        acc[(size_t)node * 2 + 0] += o0;
        acc[(size_t)node * 2 + 1] += o1;
    }
}

__global__ void finalize(const float* __restrict__ acc, const float* __restrict__ b2,
                         float* __restrict__ out, int Nrows) {
    int i = blockIdx.x * blockDim.x + threadIdx.x;
    if (i >= Nrows) return;
    float h0 = acc[2 * i] + b2[0];
    float h1 = acc[2 * i + 1] + b2[1];
    out[2 * i] = h0;
    out[2 * i + 1] = h1;
    float m = fmaxf(h0, h1);
    float e0 = expf(h0 - m), e1 = expf(h1 - m);
    float s = e0 + e1;
    out[(size_t)2 * Nrows + 2 * i] = e0 / s;
    out[(size_t)2 * Nrows + 2 * i + 1] = e1 / s;
}

// ---------------------------------------------------------------------------

extern "C" void kernel_launch(void* const* d_in, const int* in_sizes, int n_in,
                              void* d_out, int out_size, void* d_ws, size_t ws_size,
                              hipStream_t stream) {
    const int N = in_sizes[0] / GIN_N_FEAT_IN;     // 50000
    const int E = in_sizes[1] / 2;                 // 800000
    const int MP = M_PAD_ROWS;

    const float* x  = (const float*)d_in[0];
    const int*   ei = (const int*)d_in[1];
    const float* cW1[3] = {(const float*)d_in[2],  (const float*)d_in[8],  (const float*)d_in[14]};
    const float* cb1[3] = {(const float*)d_in[3],  (const float*)d_in[9],  (const float*)d_in[15]};
    const float* cg [3] = {(const float*)d_in[4],  (const float*)d_in[10], (const float*)d_in[16]};
    const float* cbe[3] = {(const float*)d_in[5],  (const float*)d_in[11], (const float*)d_in[17]};
    const float* cW2[3] = {(const float*)d_in[6],  (const float*)d_in[12], (const float*)d_in[18]};
    const float* cb2[3] = {(const float*)d_in[7],  (const float*)d_in[13], (const float*)d_in[19]};
    const float* lin1_W = (const float*)d_in[20];  // [768,768]
    const float* lin1_b = (const float*)d_in[21];
    const float* lin2_W = (const float*)d_in[22];  // [768,2]
    const float* lin2_b = (const float*)d_in[23];
    float* out = (float*)d_out;

    // ---- workspace carve-up (row buffers padded to MP rows) ----
    char* ws = (char*)d_ws;
    size_t off = 0;
    auto carve = [&](size_t bytes) {
        void* p = ws + off;
        off += (bytes + 255) & ~(size_t)255;
        return p;
    };
    ushort* Hcat   = (ushort*)carve((size_t)MP * 768 * 2);   // bf16 h1|h2|h3
    float*  hlin   = (float*) carve((size_t)MP * 256 * 4);   // f32 GEMM out
    ushort* hlin_b = (ushort*)carve((size_t)MP * 256 * 2);   // bf16 after BN
    ushort* hpre   = (ushort*)carve((size_t)MP * 256 * 2);   // bf16 agg out
    ushort* xb     = (ushort*)carve((size_t)MP * 128 * 2);   // bf16 input
    ushort* w1t[3] = {(ushort*)carve(256 * 256 * 2), (ushort*)carve(256 * 256 * 2),
                      (ushort*)carve(256 * 256 * 2)};
    ushort* w2t[3] = {(ushort*)carve(256 * 256 * 2), (ushort*)carve(256 * 256 * 2),
                      (ushort*)carve(256 * 256 * 2)};
    ushort* lin1t  = (ushort*)carve((size_t)768 * 768 * 2);
    int*   row_st  = (int*)carve((size_t)(N + 1) * 4);
    int*   cursor  = (int*)carve((size_t)N * 4);
    int*   perm    = (int*)carve((size_t)E * 4);
    float* bnsums  = (float*)carve(512 * 4);
    float* out_acc = (float*)carve((size_t)N * 2 * 4);
    (void)ws_size;

    // ---- conversions: x -> bf16, weights -> bf16 transposed ----
    cvt_f32_bf16<<<1024, 256, 0, stream>>>(x, xb, N * 64);
    transpose_cvt<<<(128 * 256 + 255) / 256, 256, 0, stream>>>(cW1[0], w1t[0], 128, 256);
    transpose_cvt<<<(256 * 256 + 255) / 256, 256, 0, stream>>>(cW1[1], w1t[1], 256, 256);
    transpose_cvt<<<(256 * 256 + 255) / 256, 256, 0, stream>>>(cW1[2], w1t[2], 256, 256);
    for (int L = 0; L < 3; ++L)
        transpose_cvt<<<(256 * 256 + 255) / 256, 256, 0, stream>>>(cW2[L], w2t[L], 256, 256);
    transpose_cvt<<<(768 * 768 + 255) / 256, 256, 0, stream>>>(lin1_W, lin1t, 768, 768);

    // ---- CSR build ----
    hipMemsetAsync(cursor, 0, (size_t)N * 4, stream);
    count_kernel<<<1024, 256, 0, stream>>>(ei, cursor, E);
    scan_kernel<<<1, 256, 0, stream>>>(cursor, row_st, N);
    hipMemcpyAsync(cursor, row_st, (size_t)N * 4, hipMemcpyDeviceToDevice, stream);
    scatter_kernel<<<1024, 256, 0, stream>>>(ei, cursor, perm, E);

    const dim3 ggrid(2, MP / 128);   // Nc=256 -> 2 col tiles

    // ---- 3 GIN conv layers ----
    for (int L = 0; L < 3; ++L) {
        const ushort* src_x = (L == 0) ? xb : (Hcat + (size_t)(L - 1) * 256);
        int stride = (L == 0) ? 128 : 768;
        int width  = (L == 0) ? 128 : 256;

        agg_bf16<<<N, width / 2, 0, stream>>>(src_x, stride, width, row_st, perm, hpre);

        // GEMM1: hpre[MP x width] * W1 + b1 -> hlin (f32)
        gemm_mfma<false, false><<<ggrid, 256, 0, stream>>>(
            hpre, w1t[L], cb1[L], hlin, 256, width);

        hipMemsetAsync(bnsums, 0, 512 * 4, stream);
        bn_stats<<<256, 256, 0, stream>>>(hlin, bnsums, N);
        bn_apply<<<2048, 256, 0, stream>>>(hlin, bnsums, cg[L], cbe[L], hlin_b, N);

        // GEMM2: hlin_b * W2 + b2, ReLU -> Hcat column block L (bf16, ldc=768)
        gemm_mfma<true, true><<<ggrid, 256, 0, stream>>>(
            hlin_b, w2t[L], cb2[L], (void*)(Hcat + (size_t)L * 256), 768, 256);
    }

    // ---- head: chunked lin1 fused into lin2 accumulation ----
    hipMemsetAsync(out_acc, 0, (size_t)N * 2 * 4, stream);
    for (int c = 0; c < 3; ++c) {
        gemm_mfma<true, false><<<ggrid, 256, 0, stream>>>(
            Hcat, lin1t + (size_t)c * 256 * 768, lin1_b + (size_t)c * 256,
            hlin, 256, 768);
        head_dot<<<(N + 3) / 4, 256, 0, stream>>>(hlin, lin2_W + (size_t)c * 512, out_acc, N);
    }
    finalize<<<(N + 255) / 256, 256, 0, stream>>>(out_acc, lin2_b, out, N);
}

// Round 4
// 984.955 us; speedup vs baseline: 2.4025x; 1.2043x over previous
//
#include <hip/hip_runtime.h>
#include <hip/hip_bf16.h>

// ---------------------------------------------------------------------------
// GIN on MI355X: bf16 MFMA GEMMs (m97 structure: 128x128 tile, BK=32,
// global_load_lds width-16, B^T operand), f32 BN stats, CSR aggregation.
// R3: hierarchical 3-stage scan replaces single-block scan (was 211 us, 18%).
// ---------------------------------------------------------------------------

#define GIN_N_FEAT_IN 128
#define GIN_H 256
#define M_PAD_ROWS 50048   // 50000 padded to 128

typedef short short8 __attribute__((ext_vector_type(8)));
typedef float f32x4 __attribute__((ext_vector_type(4)));

__device__ inline ushort f32_to_bf16(float f) {
    union { float f; uint u; } x; x.f = f;
    uint r = x.u + 0x7fff + ((x.u >> 16) & 1);
    return (ushort)(r >> 16);
}
__device__ inline float bf16_to_f32(uint h) {
    union { uint u; float f; } x; x.u = h << 16;
    return x.f;
}
__device__ inline uint pack_bf16(float lo, float hi) {
    return (uint)f32_to_bf16(lo) | ((uint)f32_to_bf16(hi) << 16);
}

__device__ inline void gload_lds16(const ushort* g, ushort* l) {
    __builtin_amdgcn_global_load_lds(
        (const __attribute__((address_space(1))) void*)g,
        (__attribute__((address_space(3))) void*)l, 16, 0, 0);
}

// ---------------- conversions ----------------

__global__ void cvt_f32_bf16(const float* __restrict__ in, ushort* __restrict__ out, int npairs) {
    for (int i = blockIdx.x * blockDim.x + threadIdx.x; i < npairs; i += gridDim.x * blockDim.x) {
        float2 v = ((const float2*)in)[i];
        ((uint*)out)[i] = pack_bf16(v.x, v.y);
    }
}

// out[c][r] = bf16(in[r][c]);  in is [R][C] row-major
__global__ void transpose_cvt(const float* __restrict__ in, ushort* __restrict__ out, int R, int C) {
    int idx = blockIdx.x * blockDim.x + threadIdx.x;
    if (idx >= R * C) return;
    int r = idx / C, c = idx - r * C;
    out[(size_t)c * R + r] = f32_to_bf16(in[idx]);
}

// ---------------- CSR build ----------------

__global__ void count_kernel(const int* __restrict__ ei, int* __restrict__ deg, int E) {
    for (int e = blockIdx.x * blockDim.x + threadIdx.x; e < E; e += gridDim.x * blockDim.x) {
        atomicAdd(&deg[ei[E + e]], 1);   // dst = ei[1][e]
    }
}

// stage 1: per-chunk (256-wide) inclusive scan; write chunk-local exclusive
// into row_start, chunk total into chunk_sums.
__global__ void scan_chunk(const int* __restrict__ deg, int* __restrict__ row_start,
                           int* __restrict__ chunk_sums, int N) {
    __shared__ int sm[256];
    int tid = threadIdx.x;
    int idx = blockIdx.x * 256 + tid;
    int v = (idx < N) ? deg[idx] : 0;
    sm[tid] = v;
    __syncthreads();
    #pragma unroll
    for (int off = 1; off < 256; off <<= 1) {
        int t = (tid >= off) ? sm[tid - off] : 0;
        __syncthreads();
        sm[tid] += t;
        __syncthreads();
    }
    if (idx < N) row_start[idx] = sm[tid] - v;          // chunk-local exclusive
    if (tid == 255) chunk_sums[blockIdx.x] = sm[255];   // chunk total
}

// stage 2: one block scans the chunk totals (nchunks <= 256) -> exclusive.
__global__ void scan_tops(int* __restrict__ chunk_sums, int* __restrict__ row_start,
                          int nchunks, int N, int E) {
    __shared__ int sm[256];
    int tid = threadIdx.x;
    int v = (tid < nchunks) ? chunk_sums[tid] : 0;
    sm[tid] = v;
    __syncthreads();
    #pragma unroll
    for (int off = 1; off < 256; off <<= 1) {
        int t = (tid >= off) ? sm[tid - off] : 0;
        __syncthreads();
        sm[tid] += t;
        __syncthreads();
    }
    if (tid < nchunks) chunk_sums[tid] = sm[tid] - v;   // exclusive chunk offset
    if (tid == 0) row_start[N] = E;
}

// stage 3: add chunk offsets; write both row_start and cursor (scatter base).
__global__ void scan_add(int* __restrict__ row_start, int* __restrict__ cursor,
                         const int* __restrict__ chunk_sums, int N) {
    int idx = blockIdx.x * 256 + threadIdx.x;
    if (idx < N) {
        int v = row_start[idx] + chunk_sums[blockIdx.x];
        row_start[idx] = v;
        cursor[idx] = v;
    }
}

__global__ void scatter_kernel(const int* __restrict__ ei, int* __restrict__ cursor,
                               int* __restrict__ perm, int E) {
    for (int e = blockIdx.x * blockDim.x + threadIdx.x; e < E; e += gridDim.x * blockDim.x) {
        int d = ei[E + e];
        int pos = atomicAdd(&cursor[d], 1);
        perm[pos] = ei[e];                                  // src = ei[0][e]
    }
}

// ---------------- aggregation (bf16 in/out, f32 accumulate) ----------------
// hpre[i] = x[i] + sum_{j in N(i)} x[j].  blockDim = width/2, thread f -> cols 2f,2f+1.

__global__ void agg_bf16(const ushort* __restrict__ xsrc, int stride, int width,
                         const int* __restrict__ row_start, const int* __restrict__ perm,
                         ushort* __restrict__ out) {
    int i = blockIdx.x;
    int f = threadIdx.x;
    int s = row_start[i], e = row_start[i + 1];
    uint v = *(const uint*)(xsrc + (size_t)i * stride + 2 * f);
    float lo = bf16_to_f32(v & 0xffffu), hi = bf16_to_f32(v >> 16);
    for (int j = s; j < e; ++j) {
        int sn = perm[j];
        uint w = *(const uint*)(xsrc + (size_t)sn * stride + 2 * f);
        lo += bf16_to_f32(w & 0xffffu);
        hi += bf16_to_f32(w >> 16);
    }
    *(uint*)(out + (size_t)i * width + 2 * f) = pack_bf16(lo, hi);
}

// ---------------- bf16 MFMA GEMM (m97 structure) ----------------
// C[M_PAD x 256] = A[M_PAD x K](bf16,row-major) * Bt[256 x K](bf16,row-major)^T
// tile 128x128, BK=32, 256 threads = 4 waves in 2x2, each wave 64x64 (4x4 frags).
// grid = (2, M_PAD/128). No M guard: all row buffers padded to M_PAD_ROWS.

template <bool RELU, bool OUT_BF16>
__global__ __launch_bounds__(256) void gemm_mfma(
    const ushort* __restrict__ A, const ushort* __restrict__ Bt,
    const float* __restrict__ bias, void* __restrict__ Cout,
    int ldc, int K) {
    __shared__ ushort As[128 * 32];
    __shared__ ushort Bs[128 * 32];
    const int tid = threadIdx.x;
    const int bm = blockIdx.y * 128;
    const int bn = blockIdx.x * 128;
    const int lane = tid & 63;
    const int wid = tid >> 6;
    const int wr = wid >> 1, wc = wid & 1;

    f32x4 acc[4][4] = {};

    // staging: pass p covers rows/cols p*64 + tid/4, k-chunk (tid&3)*8 (16B)
    const int srow = tid >> 2;
    const int skcol = (tid & 3) * 8;
    const ushort* Ag0 = A + (size_t)(bm + srow) * K + skcol;
    const ushort* Ag1 = A + (size_t)(bm + 64 + srow) * K + skcol;
    const ushort* Bg0 = Bt + (size_t)(bn + srow) * K + skcol;
    const ushort* Bg1 = Bt + (size_t)(bn + 64 + srow) * K + skcol;
    ushort* As0 = &As[(tid & ~63) * 8];          // wave-uniform base, HW adds lane*16B
    ushort* As1 = &As[2048 + (tid & ~63) * 8];
    ushort* Bs0 = &Bs[(tid & ~63) * 8];
    ushort* Bs1 = &Bs[2048 + (tid & ~63) * 8];

    const int kk = (lane >> 4) * 8;      // k-offset of this lane's fragment
    const int fr = lane & 15;            // row (A) / col (B) within fragment

    for (int k0 = 0; k0 < K; k0 += 32) {
        gload_lds16(Ag0 + k0, As0);
        gload_lds16(Ag1 + k0, As1);
        gload_lds16(Bg0 + k0, Bs0);
        gload_lds16(Bg1 + k0, Bs1);
        __syncthreads();   // compiler emits vmcnt(0) drain before barrier
        short8 af[4], bf[4];
        #pragma unroll
        for (int m = 0; m < 4; ++m)
            af[m] = *(const short8*)&As[(wr * 64 + m * 16 + fr) * 32 + kk];
        #pragma unroll
        for (int n = 0; n < 4; ++n)
            bf[n] = *(const short8*)&Bs[(wc * 64 + n * 16 + fr) * 32 + kk];
        #pragma unroll
        for (int m = 0; m < 4; ++m)
            #pragma unroll
            for (int n = 0; n < 4; ++n)
                acc[m][n] = __builtin_amdgcn_mfma_f32_16x16x32_bf16(af[m], bf[n], acc[m][n], 0, 0, 0);
        __syncthreads();
    }

    // epilogue: C/D layout col=lane&15, row=(lane>>4)*4+reg  [m89/m91 verified]
    #pragma unroll
    for (int n = 0; n < 4; ++n) {
        const int col = bn + wc * 64 + n * 16 + fr;
        const float bv = bias[col];
        #pragma unroll
        for (int m = 0; m < 4; ++m) {
            const int row0 = bm + wr * 64 + m * 16 + (lane >> 4) * 4;
            #pragma unroll
            for (int r = 0; r < 4; ++r) {
                float v = acc[m][n][r] + bv;
                if (RELU) v = fmaxf(v, 0.f);
                if (OUT_BF16)
                    ((ushort*)Cout)[(size_t)(row0 + r) * ldc + col] = f32_to_bf16(v);
                else
                    ((float*)Cout)[(size_t)(row0 + r) * ldc + col] = v;
            }
        }
    }
}

// ---------------- BatchNorm (training stats over N) ----------------

__global__ void bn_stats(const float* __restrict__ h, float* __restrict__ sums, int Nrows) {
    int col = threadIdx.x;   // 256 threads = 256 cols
    float s = 0.f, s2 = 0.f;
    for (int r = blockIdx.x; r < Nrows; r += gridDim.x) {
        float v = h[(size_t)r * 256 + col];
        s += v; s2 += v * v;
    }
    atomicAdd(&sums[col], s);
    atomicAdd(&sums[256 + col], s2);
}

// normalize + relu, write bf16 (2 cols/thread)
__global__ void bn_apply(const float* __restrict__ h, const float* __restrict__ sums,
                         const float* __restrict__ g, const float* __restrict__ be,
                         ushort* __restrict__ outb, int Nrows) {
    int total = Nrows * 128;
    float inv = 1.0f / (float)Nrows;
    for (int idx = blockIdx.x * blockDim.x + threadIdx.x; idx < total;
         idx += gridDim.x * blockDim.x) {
        int row = idx >> 7;
        int cp = (idx & 127) * 2;
        float2 v = *(const float2*)(h + (size_t)row * 256 + cp);
        float mu0 = sums[cp] * inv,     mu1 = sums[cp + 1] * inv;
        float va0 = sums[256 + cp] * inv - mu0 * mu0;
        float va1 = sums[257 + cp] * inv - mu1 * mu1;
        float o0 = fmaxf((v.x - mu0) * rsqrtf(va0 + 1e-5f) * g[cp]     + be[cp],     0.f);
        float o1 = fmaxf((v.y - mu1) * rsqrtf(va1 + 1e-5f) * g[cp + 1] + be[cp + 1], 0.f);
        *(uint*)(outb + (size_t)row * 256 + cp) = pack_bf16(o0, o1);
    }
}

// ---------------- head ----------------

__global__ void head_dot(const float* __restrict__ tchunk, const float* __restrict__ W2c,
                         float* __restrict__ acc, int Nrows) {
    int wv = threadIdx.x >> 6;
    int lane = threadIdx.x & 63;
    int node = blockIdx.x * (blockDim.x >> 6) + wv;
    if (node >= Nrows) return;
    float4 xv = *(const float4*)(tchunk + (size_t)node * 256 + lane * 4);
    float4 w01 = *(const float4*)(W2c + lane * 8);
    float4 w23 = *(const float4*)(W2c + lane * 8 + 4);
    float o0 = xv.x * w01.x + xv.y * w01.z + xv.z * w23.x + xv.w * w23.z;
    float o1 = xv.x * w01.y + xv.y * w01.w + xv.z * w23.y + xv.w * w23.w;
    #pragma unroll
    for (int off = 32; off > 0; off >>= 1) {
        o0 += __shfl_down(o0, off);
        o1 += __shfl_down(o1, off);
    }
    if (lane == 0) {
        acc[(size_t)node * 2 + 0] += o0;
        acc[(size_t)node * 2 + 1] += o1;
    }
}

__global__ void finalize(const float* __restrict__ acc, const float* __restrict__ b2,
                         float* __restrict__ out, int Nrows) {
    int i = blockIdx.x * blockDim.x + threadIdx.x;
    if (i >= Nrows) return;
    float h0 = acc[2 * i] + b2[0];
    float h1 = acc[2 * i + 1] + b2[1];
    out[2 * i] = h0;
    out[2 * i + 1] = h1;
    float m = fmaxf(h0, h1);
    float e0 = expf(h0 - m), e1 = expf(h1 - m);
    float s = e0 + e1;
    out[(size_t)2 * Nrows + 2 * i] = e0 / s;
    out[(size_t)2 * Nrows + 2 * i + 1] = e1 / s;
}

// ---------------------------------------------------------------------------

extern "C" void kernel_launch(void* const* d_in, const int* in_sizes, int n_in,
                              void* d_out, int out_size, void* d_ws, size_t ws_size,
                              hipStream_t stream) {
    const int N = in_sizes[0] / GIN_N_FEAT_IN;     // 50000
    const int E = in_sizes[1] / 2;                 // 800000
    const int MP = M_PAD_ROWS;
    const int nchunks = (N + 255) / 256;           // 196

    const float* x  = (const float*)d_in[0];
    const int*   ei = (const int*)d_in[1];
    const float* cW1[3] = {(const float*)d_in[2],  (const float*)d_in[8],  (const float*)d_in[14]};
    const float* cb1[3] = {(const float*)d_in[3],  (const float*)d_in[9],  (const float*)d_in[15]};
    const float* cg [3] = {(const float*)d_in[4],  (const float*)d_in[10], (const float*)d_in[16]};
    const float* cbe[3] = {(const float*)d_in[5],  (const float*)d_in[11], (const float*)d_in[17]};
    const float* cW2[3] = {(const float*)d_in[6],  (const float*)d_in[12], (const float*)d_in[18]};
    const float* cb2[3] = {(const float*)d_in[7],  (const float*)d_in[13], (const float*)d_in[19]};
    const float* lin1_W = (const float*)d_in[20];  // [768,768]
    const float* lin1_b = (const float*)d_in[21];
    const float* lin2_W = (const float*)d_in[22];  // [768,2]
    const float* lin2_b = (const float*)d_in[23];
    float* out = (float*)d_out;

    // ---- workspace carve-up (row buffers padded to MP rows) ----
    char* ws = (char*)d_ws;
    size_t off = 0;
    auto carve = [&](size_t bytes) {
        void* p = ws + off;
        off += (bytes + 255) & ~(size_t)255;
        return p;
    };
    ushort* Hcat   = (ushort*)carve((size_t)MP * 768 * 2);   // bf16 h1|h2|h3
    float*  hlin   = (float*) carve((size_t)MP * 256 * 4);   // f32 GEMM out
    ushort* hlin_b = (ushort*)carve((size_t)MP * 256 * 2);   // bf16 after BN
    ushort* hpre   = (ushort*)carve((size_t)MP * 256 * 2);   // bf16 agg out
    ushort* xb     = (ushort*)carve((size_t)MP * 128 * 2);   // bf16 input
    ushort* w1t[3] = {(ushort*)carve(256 * 256 * 2), (ushort*)carve(256 * 256 * 2),
                      (ushort*)carve(256 * 256 * 2)};
    ushort* w2t[3] = {(ushort*)carve(256 * 256 * 2), (ushort*)carve(256 * 256 * 2),
                      (ushort*)carve(256 * 256 * 2)};
    ushort* lin1t  = (ushort*)carve((size_t)768 * 768 * 2);
    int*   row_st  = (int*)carve((size_t)(N + 1) * 4);
    int*   cursor  = (int*)carve((size_t)N * 4);
    int*   perm    = (int*)carve((size_t)E * 4);
    int*   csums   = (int*)carve(256 * 4);
    float* bnsums  = (float*)carve(512 * 4);
    float* out_acc = (float*)carve((size_t)N * 2 * 4);
    (void)ws_size;

    // ---- conversions: x -> bf16, weights -> bf16 transposed ----
    cvt_f32_bf16<<<1024, 256, 0, stream>>>(x, xb, N * 64);
    transpose_cvt<<<(128 * 256 + 255) / 256, 256, 0, stream>>>(cW1[0], w1t[0], 128, 256);
    transpose_cvt<<<(256 * 256 + 255) / 256, 256, 0, stream>>>(cW1[1], w1t[1], 256, 256);
    transpose_cvt<<<(256 * 256 + 255) / 256, 256, 0, stream>>>(cW1[2], w1t[2], 256, 256);
    for (int L = 0; L < 3; ++L)
        transpose_cvt<<<(256 * 256 + 255) / 256, 256, 0, stream>>>(cW2[L], w2t[L], 256, 256);
    transpose_cvt<<<(768 * 768 + 255) / 256, 256, 0, stream>>>(lin1_W, lin1t, 768, 768);

    // ---- CSR build (3-stage parallel scan) ----
    hipMemsetAsync(cursor, 0, (size_t)N * 4, stream);
    count_kernel<<<1024, 256, 0, stream>>>(ei, cursor, E);
    scan_chunk<<<nchunks, 256, 0, stream>>>(cursor, row_st, csums, N);
    scan_tops<<<1, 256, 0, stream>>>(csums, row_st, nchunks, N, E);
    scan_add<<<nchunks, 256, 0, stream>>>(row_st, cursor, csums, N);
    scatter_kernel<<<1024, 256, 0, stream>>>(ei, cursor, perm, E);

    const dim3 ggrid(2, MP / 128);   // Nc=256 -> 2 col tiles

    // ---- 3 GIN conv layers ----
    for (int L = 0; L < 3; ++L) {
        const ushort* src_x = (L == 0) ? xb : (Hcat + (size_t)(L - 1) * 256);
        int stride = (L == 0) ? 128 : 768;
        int width  = (L == 0) ? 128 : 256;

        agg_bf16<<<N, width / 2, 0, stream>>>(src_x, stride, width, row_st, perm, hpre);

        // GEMM1: hpre[MP x width] * W1 + b1 -> hlin (f32)
        gemm_mfma<false, false><<<ggrid, 256, 0, stream>>>(
            hpre, w1t[L], cb1[L], hlin, 256, width);

        hipMemsetAsync(bnsums, 0, 512 * 4, stream);
        bn_stats<<<256, 256, 0, stream>>>(hlin, bnsums, N);
        bn_apply<<<2048, 256, 0, stream>>>(hlin, bnsums, cg[L], cbe[L], hlin_b, N);

        // GEMM2: hlin_b * W2 + b2, ReLU -> Hcat column block L (bf16, ldc=768)
        gemm_mfma<true, true><<<ggrid, 256, 0, stream>>>(
            hlin_b, w2t[L], cb2[L], (void*)(Hcat + (size_t)L * 256), 768, 256);
    }

    // ---- head: chunked lin1 fused into lin2 accumulation ----
    hipMemsetAsync(out_acc, 0, (size_t)N * 2 * 4, stream);
    for (int c = 0; c < 3; ++c) {
        gemm_mfma<true, false><<<ggrid, 256, 0, stream>>>(
            Hcat, lin1t + (size_t)c * 256 * 768, lin1_b + (size_t)c * 256,
            hlin, 256, 768);
        head_dot<<<(N + 3) / 4, 256, 0, stream>>>(hlin, lin2_W + (size_t)c * 512, out_acc, N);
    }
    finalize<<<(N + 255) / 256, 256, 0, stream>>>(out_acc, lin2_b, out, N);
}

// Round 5
// 725.344 us; speedup vs baseline: 3.2624x; 1.3579x over previous
//
#include <hip/hip_runtime.h>
#include <hip/hip_bf16.h>

// ---------------------------------------------------------------------------
// GIN on MI355X: bf16 MFMA GEMMs (m97 structure + XCD-bijective swizzle),
// fused BN-stats epilogue (gemm1), fused lin2 head epilogue (head gemm),
// ILP-unrolled CSR aggregation, 3-stage parallel scan.
// ---------------------------------------------------------------------------

#define GIN_N_FEAT_IN 128
#define GIN_H 256
#define M_PAD_ROWS 50048   // 50000 padded to 128

typedef short short8 __attribute__((ext_vector_type(8)));
typedef float f32x4 __attribute__((ext_vector_type(4)));

__device__ inline ushort f32_to_bf16(float f) {
    union { float f; uint u; } x; x.f = f;
    uint r = x.u + 0x7fff + ((x.u >> 16) & 1);
    return (ushort)(r >> 16);
}
__device__ inline float bf16_to_f32(uint h) {
    union { uint u; float f; } x; x.u = h << 16;
    return x.f;
}
__device__ inline uint pack_bf16(float lo, float hi) {
    return (uint)f32_to_bf16(lo) | ((uint)f32_to_bf16(hi) << 16);
}

__device__ inline void gload_lds16(const ushort* g, ushort* l) {
    __builtin_amdgcn_global_load_lds(
        (const __attribute__((address_space(1))) void*)g,
        (__attribute__((address_space(3))) void*)l, 16, 0, 0);
}

// ---------------- conversions ----------------

__global__ void cvt_f32_bf16(const float* __restrict__ in, ushort* __restrict__ out, int npairs) {
    for (int i = blockIdx.x * blockDim.x + threadIdx.x; i < npairs; i += gridDim.x * blockDim.x) {
        float2 v = ((const float2*)in)[i];
        ((uint*)out)[i] = pack_bf16(v.x, v.y);
    }
}

// out[c][r] = bf16(in[r][c]);  in is [R][C] row-major
__global__ void transpose_cvt(const float* __restrict__ in, ushort* __restrict__ out, int R, int C) {
    int idx = blockIdx.x * blockDim.x + threadIdx.x;
    if (idx >= R * C) return;
    int r = idx / C, c = idx - r * C;
    out[(size_t)c * R + r] = f32_to_bf16(in[idx]);
}

// ---------------- CSR build ----------------

__global__ void count_kernel(const int* __restrict__ ei, int* __restrict__ deg, int E) {
    for (int e = blockIdx.x * blockDim.x + threadIdx.x; e < E; e += gridDim.x * blockDim.x) {
        atomicAdd(&deg[ei[E + e]], 1);   // dst = ei[1][e]
    }
}

__global__ void scan_chunk(const int* __restrict__ deg, int* __restrict__ row_start,
                           int* __restrict__ chunk_sums, int N) {
    __shared__ int sm[256];
    int tid = threadIdx.x;
    int idx = blockIdx.x * 256 + tid;
    int v = (idx < N) ? deg[idx] : 0;
    sm[tid] = v;
    __syncthreads();
    #pragma unroll
    for (int off = 1; off < 256; off <<= 1) {
        int t = (tid >= off) ? sm[tid - off] : 0;
        __syncthreads();
        sm[tid] += t;
        __syncthreads();
    }
    if (idx < N) row_start[idx] = sm[tid] - v;
    if (tid == 255) chunk_sums[blockIdx.x] = sm[255];
}

__global__ void scan_tops(int* __restrict__ chunk_sums, int* __restrict__ row_start,
                          int nchunks, int N, int E) {
    __shared__ int sm[256];
    int tid = threadIdx.x;
    int v = (tid < nchunks) ? chunk_sums[tid] : 0;
    sm[tid] = v;
    __syncthreads();
    #pragma unroll
    for (int off = 1; off < 256; off <<= 1) {
        int t = (tid >= off) ? sm[tid - off] : 0;
        __syncthreads();
        sm[tid] += t;
        __syncthreads();
    }
    if (tid < nchunks) chunk_sums[tid] = sm[tid] - v;
    if (tid == 0) row_start[N] = E;
}

__global__ void scan_add(int* __restrict__ row_start, int* __restrict__ cursor,
                         const int* __restrict__ chunk_sums, int N) {
    int idx = blockIdx.x * 256 + threadIdx.x;
    if (idx < N) {
        int v = row_start[idx] + chunk_sums[blockIdx.x];
        row_start[idx] = v;
        cursor[idx] = v;
    }
}

__global__ void scatter_kernel(const int* __restrict__ ei, int* __restrict__ cursor,
                               int* __restrict__ perm, int E) {
    for (int e = blockIdx.x * blockDim.x + threadIdx.x; e < E; e += gridDim.x * blockDim.x) {
        int d = ei[E + e];
        int pos = atomicAdd(&cursor[d], 1);
        perm[pos] = ei[e];
    }
}

// ---------------- aggregation: wave-per-node, unroll-4 ILP ----------------
// hpre[i] = x[i] + sum_{j in N(i)} x[j].  W = feature width (128 or 256).

template <int W>
__global__ void agg2(const ushort* __restrict__ xsrc, int stride,
                     const int* __restrict__ row_start, const int* __restrict__ perm,
                     ushort* __restrict__ out, int N) {
    constexpr int PL = W / 64;                 // bf16 per lane: 2 or 4
    int node = blockIdx.x * 4 + (threadIdx.x >> 6);
    if (node >= N) return;
    const int lane = threadIdx.x & 63;
    const size_t loff = (size_t)lane * PL;

    float af[PL];
    {
        const ushort* p = xsrc + (size_t)node * stride + loff;
        if constexpr (W == 256) {
            uint2 v = *(const uint2*)p;
            af[0] = bf16_to_f32(v.x & 0xffffu); af[1] = bf16_to_f32(v.x >> 16);
            af[2] = bf16_to_f32(v.y & 0xffffu); af[3] = bf16_to_f32(v.y >> 16);
        } else {
            uint v = *(const uint*)p;
            af[0] = bf16_to_f32(v & 0xffffu); af[1] = bf16_to_f32(v >> 16);
        }
    }
    const int s = row_start[node], e = row_start[node + 1];
    int j = s;
    for (; j + 4 <= e; j += 4) {
        int n0 = perm[j], n1 = perm[j + 1], n2 = perm[j + 2], n3 = perm[j + 3];
        if constexpr (W == 256) {
            uint2 w0 = *(const uint2*)(xsrc + (size_t)n0 * stride + loff);
            uint2 w1 = *(const uint2*)(xsrc + (size_t)n1 * stride + loff);
            uint2 w2 = *(const uint2*)(xsrc + (size_t)n2 * stride + loff);
            uint2 w3 = *(const uint2*)(xsrc + (size_t)n3 * stride + loff);
            af[0] += bf16_to_f32(w0.x & 0xffffu) + bf16_to_f32(w1.x & 0xffffu)
                   + bf16_to_f32(w2.x & 0xffffu) + bf16_to_f32(w3.x & 0xffffu);
            af[1] += bf16_to_f32(w0.x >> 16) + bf16_to_f32(w1.x >> 16)
                   + bf16_to_f32(w2.x >> 16) + bf16_to_f32(w3.x >> 16);
            af[2] += bf16_to_f32(w0.y & 0xffffu) + bf16_to_f32(w1.y & 0xffffu)
                   + bf16_to_f32(w2.y & 0xffffu) + bf16_to_f32(w3.y & 0xffffu);
            af[3] += bf16_to_f32(w0.y >> 16) + bf16_to_f32(w1.y >> 16)
                   + bf16_to_f32(w2.y >> 16) + bf16_to_f32(w3.y >> 16);
        } else {
            uint w0 = *(const uint*)(xsrc + (size_t)n0 * stride + loff);
            uint w1 = *(const uint*)(xsrc + (size_t)n1 * stride + loff);
            uint w2 = *(const uint*)(xsrc + (size_t)n2 * stride + loff);
            uint w3 = *(const uint*)(xsrc + (size_t)n3 * stride + loff);
            af[0] += bf16_to_f32(w0 & 0xffffu) + bf16_to_f32(w1 & 0xffffu)
                   + bf16_to_f32(w2 & 0xffffu) + bf16_to_f32(w3 & 0xffffu);
            af[1] += bf16_to_f32(w0 >> 16) + bf16_to_f32(w1 >> 16)
                   + bf16_to_f32(w2 >> 16) + bf16_to_f32(w3 >> 16);
        }
    }
    for (; j < e; ++j) {
        int sn = perm[j];
        const ushort* p = xsrc + (size_t)sn * stride + loff;
        if constexpr (W == 256) {
            uint2 w = *(const uint2*)p;
            af[0] += bf16_to_f32(w.x & 0xffffu); af[1] += bf16_to_f32(w.x >> 16);
            af[2] += bf16_to_f32(w.y & 0xffffu); af[3] += bf16_to_f32(w.y >> 16);
        } else {
            uint w = *(const uint*)p;
            af[0] += bf16_to_f32(w & 0xffffu); af[1] += bf16_to_f32(w >> 16);
        }
    }
    ushort* po = out + (size_t)node * W + loff;
    if constexpr (W == 256) {
        uint2 o; o.x = pack_bf16(af[0], af[1]); o.y = pack_bf16(af[2], af[3]);
        *(uint2*)po = o;
    } else {
        *(uint*)po = pack_bf16(af[0], af[1]);
    }
}

// ---------------- bf16 MFMA GEMM (m97 structure + XCD swizzle) ----------------
// C[M_PAD x Nc] = A[M_PAD x K](bf16,rm) * Bt[Nc x K](bf16,rm)^T.
// tile 128x128, BK=32, 4 waves 2x2, 4x4 16x16 frags. grid=(Nc/128, MP/128).
// MODE 0: f32 store + fused BN col-stats (extra=bnsums[512])
// MODE 1: bf16 store + relu
// MODE 2: no store; fused head: atomicAdd relu(v)@w2 -> out_acc (extra=out_acc)

template <int MODE>
__global__ __launch_bounds__(256) void gemm_mfma(
    const ushort* __restrict__ A, const ushort* __restrict__ Bt,
    const float* __restrict__ bias, void* __restrict__ Cout,
    int ldc, int K, const float* __restrict__ w2,
    float* __restrict__ extra, int Nvalid) {
    __shared__ ushort As[128 * 32];
    __shared__ ushort Bs[128 * 32];
    const int tid = threadIdx.x;

    // XCD-bijective chunked swizzle (m204): contiguous logical tiles per XCD.
    const int gx = gridDim.x;
    const int nwg = gx * gridDim.y;
    const int flat = blockIdx.y * gx + blockIdx.x;
    const int q = nwg >> 3, r = nwg & 7;
    const int xcd = flat & 7, loc = flat >> 3;
    const int wg = (xcd < r ? xcd * (q + 1) : r * (q + 1) + (xcd - r) * q) + loc;
    const int bm = (wg / gx) * 128;
    const int bn = (wg % gx) * 128;

    const int lane = tid & 63;
    const int wid = tid >> 6;
    const int wr = wid >> 1, wc = wid & 1;

    f32x4 acc[4][4] = {};

    const int srow = tid >> 2;
    const int skcol = (tid & 3) * 8;
    const ushort* Ag0 = A + (size_t)(bm + srow) * K + skcol;
    const ushort* Ag1 = A + (size_t)(bm + 64 + srow) * K + skcol;
    const ushort* Bg0 = Bt + (size_t)(bn + srow) * K + skcol;
    const ushort* Bg1 = Bt + (size_t)(bn + 64 + srow) * K + skcol;
    ushort* As0 = &As[(tid & ~63) * 8];
    ushort* As1 = &As[2048 + (tid & ~63) * 8];
    ushort* Bs0 = &Bs[(tid & ~63) * 8];
    ushort* Bs1 = &Bs[2048 + (tid & ~63) * 8];

    const int kk = (lane >> 4) * 8;
    const int fr = lane & 15;

    for (int k0 = 0; k0 < K; k0 += 32) {
        gload_lds16(Ag0 + k0, As0);
        gload_lds16(Ag1 + k0, As1);
        gload_lds16(Bg0 + k0, Bs0);
        gload_lds16(Bg1 + k0, Bs1);
        __syncthreads();
        short8 af[4], bf[4];
        #pragma unroll
        for (int m = 0; m < 4; ++m)
            af[m] = *(const short8*)&As[(wr * 64 + m * 16 + fr) * 32 + kk];
        #pragma unroll
        for (int n = 0; n < 4; ++n)
            bf[n] = *(const short8*)&Bs[(wc * 64 + n * 16 + fr) * 32 + kk];
        #pragma unroll
        for (int m = 0; m < 4; ++m)
            #pragma unroll
            for (int n = 0; n < 4; ++n)
                acc[m][n] = __builtin_amdgcn_mfma_f32_16x16x32_bf16(af[m], bf[n], acc[m][n], 0, 0, 0);
        __syncthreads();
    }

    // epilogue: C/D layout col=lane&15, row=(lane>>4)*4+reg
    if constexpr (MODE == 2) {
        // fused head: out_acc[row] += relu(v + bias) @ w2[col][0..1]
        #pragma unroll
        for (int m = 0; m < 4; ++m) {
            #pragma unroll
            for (int rr = 0; rr < 4; ++rr) {
                float o0 = 0.f, o1 = 0.f;
                #pragma unroll
                for (int n = 0; n < 4; ++n) {
                    int col = bn + wc * 64 + n * 16 + fr;
                    float v = fmaxf(acc[m][n][rr] + bias[col], 0.f);
                    o0 = fmaf(v, w2[col * 2 + 0], o0);
                    o1 = fmaf(v, w2[col * 2 + 1], o1);
                }
                o0 += __shfl_xor(o0, 1); o1 += __shfl_xor(o1, 1);
                o0 += __shfl_xor(o0, 2); o1 += __shfl_xor(o1, 2);
                o0 += __shfl_xor(o0, 4); o1 += __shfl_xor(o1, 4);
                o0 += __shfl_xor(o0, 8); o1 += __shfl_xor(o1, 8);
                int row = bm + wr * 64 + m * 16 + (lane >> 4) * 4 + rr;
                if (fr == 0 && row < Nvalid) {
                    atomicAdd(&extra[(size_t)row * 2 + 0], o0);
                    atomicAdd(&extra[(size_t)row * 2 + 1], o1);
                }
            }
        }
    } else {
        float s1[4], s2[4];
        if constexpr (MODE == 0) {
            #pragma unroll
            for (int n = 0; n < 4; ++n) { s1[n] = 0.f; s2[n] = 0.f; }
        }
        #pragma unroll
        for (int n = 0; n < 4; ++n) {
            const int col = bn + wc * 64 + n * 16 + fr;
            const float bv = bias[col];
            #pragma unroll
            for (int m = 0; m < 4; ++m) {
                const int row0 = bm + wr * 64 + m * 16 + (lane >> 4) * 4;
                #pragma unroll
                for (int rr = 0; rr < 4; ++rr) {
                    float v = acc[m][n][rr] + bv;
                    if constexpr (MODE == 1) {
                        v = fmaxf(v, 0.f);
                        ((ushort*)Cout)[(size_t)(row0 + rr) * ldc + col] = f32_to_bf16(v);
                    } else {
                        ((float*)Cout)[(size_t)(row0 + rr) * ldc + col] = v;
                        if (row0 + rr < Nvalid) { s1[n] += v; s2[n] += v * v; }
                    }
                }
            }
        }
        if constexpr (MODE == 0) {
            #pragma unroll
            for (int n = 0; n < 4; ++n) {
                float a = s1[n], b = s2[n];
                a += __shfl_xor(a, 16); b += __shfl_xor(b, 16);
                a += __shfl_xor(a, 32); b += __shfl_xor(b, 32);
                if ((lane >> 4) == 0) {
                    int col = bn + wc * 64 + n * 16 + fr;
                    atomicAdd(&extra[col], a);
                    atomicAdd(&extra[256 + col], b);
                }
            }
        }
    }
}

// ---------------- BN apply (normalize + relu, write bf16) ----------------

__global__ void bn_apply(const float* __restrict__ h, const float* __restrict__ sums,
                         const float* __restrict__ g, const float* __restrict__ be,
                         ushort* __restrict__ outb, int Nrows) {
    int total = Nrows * 128;
    float inv = 1.0f / (float)Nrows;
    for (int idx = blockIdx.x * blockDim.x + threadIdx.x; idx < total;
         idx += gridDim.x * blockDim.x) {
        int row = idx >> 7;
        int cp = (idx & 127) * 2;
        float2 v = *(const float2*)(h + (size_t)row * 256 + cp);
        float mu0 = sums[cp] * inv,     mu1 = sums[cp + 1] * inv;
        float va0 = sums[256 + cp] * inv - mu0 * mu0;
        float va1 = sums[257 + cp] * inv - mu1 * mu1;
        float o0 = fmaxf((v.x - mu0) * rsqrtf(va0 + 1e-5f) * g[cp]     + be[cp],     0.f);
        float o1 = fmaxf((v.y - mu1) * rsqrtf(va1 + 1e-5f) * g[cp + 1] + be[cp + 1], 0.f);
        *(uint*)(outb + (size_t)row * 256 + cp) = pack_bf16(o0, o1);
    }
}

// ---------------- finalize: bias + softmax ----------------

__global__ void finalize(const float* __restrict__ acc, const float* __restrict__ b2,
                         float* __restrict__ out, int Nrows) {
    int i = blockIdx.x * blockDim.x + threadIdx.x;
    if (i >= Nrows) return;
    float h0 = acc[2 * i] + b2[0];
    float h1 = acc[2 * i + 1] + b2[1];
    out[2 * i] = h0;
    out[2 * i + 1] = h1;
    float m = fmaxf(h0, h1);
    float e0 = expf(h0 - m), e1 = expf(h1 - m);
    float s = e0 + e1;
    out[(size_t)2 * Nrows + 2 * i] = e0 / s;
    out[(size_t)2 * Nrows + 2 * i + 1] = e1 / s;
}

// ---------------------------------------------------------------------------

extern "C" void kernel_launch(void* const* d_in, const int* in_sizes, int n_in,
                              void* d_out, int out_size, void* d_ws, size_t ws_size,
                              hipStream_t stream) {
    const int N = in_sizes[0] / GIN_N_FEAT_IN;     // 50000
    const int E = in_sizes[1] / 2;                 // 800000
    const int MP = M_PAD_ROWS;
    const int nchunks = (N + 255) / 256;           // 196

    const float* x  = (const float*)d_in[0];
    const int*   ei = (const int*)d_in[1];
    const float* cW1[3] = {(const float*)d_in[2],  (const float*)d_in[8],  (const float*)d_in[14]};
    const float* cb1[3] = {(const float*)d_in[3],  (const float*)d_in[9],  (const float*)d_in[15]};
    const float* cg [3] = {(const float*)d_in[4],  (const float*)d_in[10], (const float*)d_in[16]};
    const float* cbe[3] = {(const float*)d_in[5],  (const float*)d_in[11], (const float*)d_in[17]};
    const float* cW2[3] = {(const float*)d_in[6],  (const float*)d_in[12], (const float*)d_in[18]};
    const float* cb2[3] = {(const float*)d_in[7],  (const float*)d_in[13], (const float*)d_in[19]};
    const float* lin1_W = (const float*)d_in[20];  // [768,768]
    const float* lin1_b = (const float*)d_in[21];
    const float* lin2_W = (const float*)d_in[22];  // [768,2]
    const float* lin2_b = (const float*)d_in[23];
    float* out = (float*)d_out;

    // ---- workspace carve-up (row buffers padded to MP rows) ----
    char* ws = (char*)d_ws;
    size_t off = 0;
    auto carve = [&](size_t bytes) {
        void* p = ws + off;
        off += (bytes + 255) & ~(size_t)255;
        return p;
    };
    ushort* Hcat   = (ushort*)carve((size_t)MP * 768 * 2);   // bf16 h1|h2|h3
    float*  hlin   = (float*) carve((size_t)MP * 256 * 4);   // f32 gemm1 out
    ushort* hlin_b = (ushort*)carve((size_t)MP * 256 * 2);   // bf16 after BN
    ushort* hpre   = (ushort*)carve((size_t)MP * 256 * 2);   // bf16 agg out
    ushort* xb     = (ushort*)carve((size_t)MP * 128 * 2);   // bf16 input
    ushort* w1t[3] = {(ushort*)carve(256 * 256 * 2), (ushort*)carve(256 * 256 * 2),
                      (ushort*)carve(256 * 256 * 2)};
    ushort* w2t[3] = {(ushort*)carve(256 * 256 * 2), (ushort*)carve(256 * 256 * 2),
                      (ushort*)carve(256 * 256 * 2)};
    ushort* lin1t  = (ushort*)carve((size_t)768 * 768 * 2);
    int*   row_st  = (int*)carve((size_t)(N + 1) * 4);
    int*   cursor  = (int*)carve((size_t)N * 4);
    int*   perm    = (int*)carve((size_t)E * 4);
    int*   csums   = (int*)carve(256 * 4);
    float* bnsums  = (float*)carve(512 * 4);
    float* out_acc = (float*)carve((size_t)N * 2 * 4);
    (void)ws_size;

    // ---- conversions ----
    cvt_f32_bf16<<<1024, 256, 0, stream>>>(x, xb, N * 64);
    transpose_cvt<<<(128 * 256 + 255) / 256, 256, 0, stream>>>(cW1[0], w1t[0], 128, 256);
    transpose_cvt<<<(256 * 256 + 255) / 256, 256, 0, stream>>>(cW1[1], w1t[1], 256, 256);
    transpose_cvt<<<(256 * 256 + 255) / 256, 256, 0, stream>>>(cW1[2], w1t[2], 256, 256);
    for (int L = 0; L < 3; ++L)
        transpose_cvt<<<(256 * 256 + 255) / 256, 256, 0, stream>>>(cW2[L], w2t[L], 256, 256);
    transpose_cvt<<<(768 * 768 + 255) / 256, 256, 0, stream>>>(lin1_W, lin1t, 768, 768);

    // ---- CSR build (3-stage parallel scan) ----
    hipMemsetAsync(cursor, 0, (size_t)N * 4, stream);
    count_kernel<<<1024, 256, 0, stream>>>(ei, cursor, E);
    scan_chunk<<<nchunks, 256, 0, stream>>>(cursor, row_st, csums, N);
    scan_tops<<<1, 256, 0, stream>>>(csums, row_st, nchunks, N, E);
    scan_add<<<nchunks, 256, 0, stream>>>(row_st, cursor, csums, N);
    scatter_kernel<<<1024, 256, 0, stream>>>(ei, cursor, perm, E);

    const dim3 ggrid(2, MP / 128);       // Nc=256
    const int aggblocks = (N + 3) / 4;   // wave per node

    // ---- 3 GIN conv layers ----
    for (int L = 0; L < 3; ++L) {
        if (L == 0)
            agg2<128><<<aggblocks, 256, 0, stream>>>(xb, 128, row_st, perm, hpre, N);
        else
            agg2<256><<<aggblocks, 256, 0, stream>>>(Hcat + (size_t)(L - 1) * 256, 768,
                                                     row_st, perm, hpre, N);

        // GEMM1 + fused BN stats: hpre * W1 + b1 -> hlin (f32), bnsums
        hipMemsetAsync(bnsums, 0, 512 * 4, stream);
        gemm_mfma<0><<<ggrid, 256, 0, stream>>>(
            hpre, w1t[L], cb1[L], hlin, 256, (L == 0) ? 128 : 256,
            nullptr, bnsums, N);

        bn_apply<<<2048, 256, 0, stream>>>(hlin, bnsums, cg[L], cbe[L], hlin_b, N);

        // GEMM2: hlin_b * W2 + b2, ReLU -> Hcat column block L (bf16, ldc=768)
        gemm_mfma<1><<<ggrid, 256, 0, stream>>>(
            hlin_b, w2t[L], cb2[L], (void*)(Hcat + (size_t)L * 256), 768, 256,
            nullptr, nullptr, 0);
    }

    // ---- head: single fused gemm (lin1 768->768, relu, dot lin2) ----
    hipMemsetAsync(out_acc, 0, (size_t)N * 2 * 4, stream);
    gemm_mfma<2><<<dim3(6, MP / 128), 256, 0, stream>>>(
        Hcat, lin1t, lin1_b, nullptr, 0, 768, lin2_W, out_acc, N);

    finalize<<<(N + 255) / 256, 256, 0, stream>>>(out_acc, lin2_b, out, N);
}

// Round 6
// 686.934 us; speedup vs baseline: 3.4449x; 1.0559x over previous
//
#include <hip/hip_runtime.h>
#include <hip/hip_bf16.h>

// ---------------------------------------------------------------------------
// GIN on MI355X: bf16 MFMA GEMMs. Conv layers: m97 128x128/BK=32 structure
// with fused BN-stats epilogue. Head: 256x128/BK=64 8-wave GEMM with fused
// relu+lin2 dot, LDS-combined atomic-free partial stores.
// ---------------------------------------------------------------------------

#define GIN_N_FEAT_IN 128
#define GIN_H 256
#define M_PAD_ROWS 50176   // 50000 padded to 256 (head tile height)

typedef short short8 __attribute__((ext_vector_type(8)));
typedef float f32x4 __attribute__((ext_vector_type(4)));

__device__ inline ushort f32_to_bf16(float f) {
    union { float f; uint u; } x; x.f = f;
    uint r = x.u + 0x7fff + ((x.u >> 16) & 1);
    return (ushort)(r >> 16);
}
__device__ inline float bf16_to_f32(uint h) {
    union { uint u; float f; } x; x.u = h << 16;
    return x.f;
}
__device__ inline uint pack_bf16(float lo, float hi) {
    return (uint)f32_to_bf16(lo) | ((uint)f32_to_bf16(hi) << 16);
}

__device__ inline void gload_lds16(const ushort* g, ushort* l) {
    __builtin_amdgcn_global_load_lds(
        (const __attribute__((address_space(1))) void*)g,
        (__attribute__((address_space(3))) void*)l, 16, 0, 0);
}

// ---------------- conversions ----------------

__global__ void cvt_f32_bf16(const float* __restrict__ in, ushort* __restrict__ out, int npairs) {
    for (int i = blockIdx.x * blockDim.x + threadIdx.x; i < npairs; i += gridDim.x * blockDim.x) {
        float2 v = ((const float2*)in)[i];
        ((uint*)out)[i] = pack_bf16(v.x, v.y);
    }
}

// all weight transposes in one dispatch: dst[c][r] = bf16(src[r][c])
struct WPrep {
    const float* src[7];
    ushort* dst[7];
    int R[7];
    int C[7];
};

__global__ void prep_weights(WPrep p) {
    int which = blockIdx.y;
    int R = p.R[which], C = p.C[which];
    int total = R * C;
    const float* src = p.src[which];
    ushort* dst = p.dst[which];
    for (int idx = blockIdx.x * blockDim.x + threadIdx.x; idx < total;
         idx += gridDim.x * blockDim.x) {
        int r = idx / C, c = idx - r * C;
        dst[(size_t)c * R + r] = f32_to_bf16(src[idx]);
    }
}

// ---------------- CSR build ----------------

__global__ void count_kernel(const int* __restrict__ ei, int* __restrict__ deg, int E) {
    for (int e = blockIdx.x * blockDim.x + threadIdx.x; e < E; e += gridDim.x * blockDim.x) {
        atomicAdd(&deg[ei[E + e]], 1);   // dst = ei[1][e]
    }
}

__global__ void scan_chunk(const int* __restrict__ deg, int* __restrict__ row_start,
                           int* __restrict__ chunk_sums, int N) {
    __shared__ int sm[256];
    int tid = threadIdx.x;
    int idx = blockIdx.x * 256 + tid;
    int v = (idx < N) ? deg[idx] : 0;
    sm[tid] = v;
    __syncthreads();
    #pragma unroll
    for (int off = 1; off < 256; off <<= 1) {
        int t = (tid >= off) ? sm[tid - off] : 0;
        __syncthreads();
        sm[tid] += t;
        __syncthreads();
    }
    if (idx < N) row_start[idx] = sm[tid] - v;
    if (tid == 255) chunk_sums[blockIdx.x] = sm[255];
}

__global__ void scan_tops(int* __restrict__ chunk_sums, int* __restrict__ row_start,
                          int nchunks, int N, int E) {
    __shared__ int sm[256];
    int tid = threadIdx.x;
    int v = (tid < nchunks) ? chunk_sums[tid] : 0;
    sm[tid] = v;
    __syncthreads();
    #pragma unroll
    for (int off = 1; off < 256; off <<= 1) {
        int t = (tid >= off) ? sm[tid - off] : 0;
        __syncthreads();
        sm[tid] += t;
        __syncthreads();
    }
    if (tid < nchunks) chunk_sums[tid] = sm[tid] - v;
    if (tid == 0) row_start[N] = E;
}

__global__ void scan_add(int* __restrict__ row_start, int* __restrict__ cursor,
                         const int* __restrict__ chunk_sums, int N) {
    int idx = blockIdx.x * 256 + threadIdx.x;
    if (idx < N) {
        int v = row_start[idx] + chunk_sums[blockIdx.x];
        row_start[idx] = v;
        cursor[idx] = v;
    }
}

__global__ void scatter_kernel(const int* __restrict__ ei, int* __restrict__ cursor,
                               int* __restrict__ perm, int E) {
    for (int e = blockIdx.x * blockDim.x + threadIdx.x; e < E; e += gridDim.x * blockDim.x) {
        int d = ei[E + e];
        int pos = atomicAdd(&cursor[d], 1);
        perm[pos] = ei[e];
    }
}

// ---------------- aggregation: wave-per-node, unroll-4 ILP ----------------

template <int W>
__global__ void agg2(const ushort* __restrict__ xsrc, int stride,
                     const int* __restrict__ row_start, const int* __restrict__ perm,
                     ushort* __restrict__ out, int N) {
    constexpr int PL = W / 64;                 // bf16 per lane: 2 or 4
    int node = blockIdx.x * 4 + (threadIdx.x >> 6);
    if (node >= N) return;
    const int lane = threadIdx.x & 63;
    const size_t loff = (size_t)lane * PL;

    float af[PL];
    {
        const ushort* p = xsrc + (size_t)node * stride + loff;
        if constexpr (W == 256) {
            uint2 v = *(const uint2*)p;
            af[0] = bf16_to_f32(v.x & 0xffffu); af[1] = bf16_to_f32(v.x >> 16);
            af[2] = bf16_to_f32(v.y & 0xffffu); af[3] = bf16_to_f32(v.y >> 16);
        } else {
            uint v = *(const uint*)p;
            af[0] = bf16_to_f32(v & 0xffffu); af[1] = bf16_to_f32(v >> 16);
        }
    }
    const int s = row_start[node], e = row_start[node + 1];
    int j = s;
    for (; j + 4 <= e; j += 4) {
        int n0 = perm[j], n1 = perm[j + 1], n2 = perm[j + 2], n3 = perm[j + 3];
        if constexpr (W == 256) {
            uint2 w0 = *(const uint2*)(xsrc + (size_t)n0 * stride + loff);
            uint2 w1 = *(const uint2*)(xsrc + (size_t)n1 * stride + loff);
            uint2 w2 = *(const uint2*)(xsrc + (size_t)n2 * stride + loff);
            uint2 w3 = *(const uint2*)(xsrc + (size_t)n3 * stride + loff);
            af[0] += bf16_to_f32(w0.x & 0xffffu) + bf16_to_f32(w1.x & 0xffffu)
                   + bf16_to_f32(w2.x & 0xffffu) + bf16_to_f32(w3.x & 0xffffu);
            af[1] += bf16_to_f32(w0.x >> 16) + bf16_to_f32(w1.x >> 16)
                   + bf16_to_f32(w2.x >> 16) + bf16_to_f32(w3.x >> 16);
            af[2] += bf16_to_f32(w0.y & 0xffffu) + bf16_to_f32(w1.y & 0xffffu)
                   + bf16_to_f32(w2.y & 0xffffu) + bf16_to_f32(w3.y & 0xffffu);
            af[3] += bf16_to_f32(w0.y >> 16) + bf16_to_f32(w1.y >> 16)
                   + bf16_to_f32(w2.y >> 16) + bf16_to_f32(w3.y >> 16);
        } else {
            uint w0 = *(const uint*)(xsrc + (size_t)n0 * stride + loff);
            uint w1 = *(const uint*)(xsrc + (size_t)n1 * stride + loff);
            uint w2 = *(const uint*)(xsrc + (size_t)n2 * stride + loff);
            uint w3 = *(const uint*)(xsrc + (size_t)n3 * stride + loff);
            af[0] += bf16_to_f32(w0 & 0xffffu) + bf16_to_f32(w1 & 0xffffu)
                   + bf16_to_f32(w2 & 0xffffu) + bf16_to_f32(w3 & 0xffffu);
            af[1] += bf16_to_f32(w0 >> 16) + bf16_to_f32(w1 >> 16)
                   + bf16_to_f32(w2 >> 16) + bf16_to_f32(w3 >> 16);
        }
    }
    for (; j < e; ++j) {
        int sn = perm[j];
        const ushort* p = xsrc + (size_t)sn * stride + loff;
        if constexpr (W == 256) {
            uint2 w = *(const uint2*)p;
            af[0] += bf16_to_f32(w.x & 0xffffu); af[1] += bf16_to_f32(w.x >> 16);
            af[2] += bf16_to_f32(w.y & 0xffffu); af[3] += bf16_to_f32(w.y >> 16);
        } else {
            uint w = *(const uint*)p;
            af[0] += bf16_to_f32(w & 0xffffu); af[1] += bf16_to_f32(w >> 16);
        }
    }
    ushort* po = out + (size_t)node * W + loff;
    if constexpr (W == 256) {
        uint2 o; o.x = pack_bf16(af[0], af[1]); o.y = pack_bf16(af[2], af[3]);
        *(uint2*)po = o;
    } else {
        *(uint*)po = pack_bf16(af[0], af[1]);
    }
}

// ---------------- conv bf16 MFMA GEMM (m97 structure + XCD swizzle) ----------
// C[MP x 256] = A[MP x K] * Bt[256 x K]^T.  tile 128x128, BK=32, 4 waves.
// MODE 0: f32 store + fused BN col-stats (extra=bnsums[512])
// MODE 1: bf16 store + relu

template <int MODE>
__global__ __launch_bounds__(256) void gemm_mfma(
    const ushort* __restrict__ A, const ushort* __restrict__ Bt,
    const float* __restrict__ bias, void* __restrict__ Cout,
    int ldc, int K, float* __restrict__ extra, int Nvalid) {
    __shared__ ushort As[128 * 32];
    __shared__ ushort Bs[128 * 32];
    const int tid = threadIdx.x;

    // XCD-bijective chunked swizzle (m204)
    const int gx = gridDim.x;
    const int nwg = gx * gridDim.y;
    const int flat = blockIdx.y * gx + blockIdx.x;
    const int q = nwg >> 3, r = nwg & 7;
    const int xcd = flat & 7, loc = flat >> 3;
    const int wg = (xcd < r ? xcd * (q + 1) : r * (q + 1) + (xcd - r) * q) + loc;
    const int bm = (wg / gx) * 128;
    const int bn = (wg % gx) * 128;

    const int lane = tid & 63;
    const int wid = tid >> 6;
    const int wr = wid >> 1, wc = wid & 1;

    f32x4 acc[4][4] = {};

    const int srow = tid >> 2;
    const int skcol = (tid & 3) * 8;
    const ushort* Ag0 = A + (size_t)(bm + srow) * K + skcol;
    const ushort* Ag1 = A + (size_t)(bm + 64 + srow) * K + skcol;
    const ushort* Bg0 = Bt + (size_t)(bn + srow) * K + skcol;
    const ushort* Bg1 = Bt + (size_t)(bn + 64 + srow) * K + skcol;
    ushort* As0 = &As[(tid & ~63) * 8];
    ushort* As1 = &As[2048 + (tid & ~63) * 8];
    ushort* Bs0 = &Bs[(tid & ~63) * 8];
    ushort* Bs1 = &Bs[2048 + (tid & ~63) * 8];

    const int kk = (lane >> 4) * 8;
    const int fr = lane & 15;

    for (int k0 = 0; k0 < K; k0 += 32) {
        gload_lds16(Ag0 + k0, As0);
        gload_lds16(Ag1 + k0, As1);
        gload_lds16(Bg0 + k0, Bs0);
        gload_lds16(Bg1 + k0, Bs1);
        __syncthreads();
        short8 af[4], bf[4];
        #pragma unroll
        for (int m = 0; m < 4; ++m)
            af[m] = *(const short8*)&As[(wr * 64 + m * 16 + fr) * 32 + kk];
        #pragma unroll
        for (int n = 0; n < 4; ++n)
            bf[n] = *(const short8*)&Bs[(wc * 64 + n * 16 + fr) * 32 + kk];
        #pragma unroll
        for (int m = 0; m < 4; ++m)
            #pragma unroll
            for (int n = 0; n < 4; ++n)
                acc[m][n] = __builtin_amdgcn_mfma_f32_16x16x32_bf16(af[m], bf[n], acc[m][n], 0, 0, 0);
        __syncthreads();
    }

    // epilogue: C/D layout col=lane&15, row=(lane>>4)*4+reg
    float s1[4], s2[4];
    if constexpr (MODE == 0) {
        #pragma unroll
        for (int n = 0; n < 4; ++n) { s1[n] = 0.f; s2[n] = 0.f; }
    }
    #pragma unroll
    for (int n = 0; n < 4; ++n) {
        const int col = bn + wc * 64 + n * 16 + fr;
        const float bv = bias[col];
        #pragma unroll
        for (int m = 0; m < 4; ++m) {
            const int row0 = bm + wr * 64 + m * 16 + (lane >> 4) * 4;
            #pragma unroll
            for (int rr = 0; rr < 4; ++rr) {
                float v = acc[m][n][rr] + bv;
                if constexpr (MODE == 1) {
                    v = fmaxf(v, 0.f);
                    ((ushort*)Cout)[(size_t)(row0 + rr) * ldc + col] = f32_to_bf16(v);
                } else {
                    ((float*)Cout)[(size_t)(row0 + rr) * ldc + col] = v;
                    if (row0 + rr < Nvalid) { s1[n] += v; s2[n] += v * v; }
                }
            }
        }
    }
    if constexpr (MODE == 0) {
        #pragma unroll
        for (int n = 0; n < 4; ++n) {
            float a = s1[n], b = s2[n];
            a += __shfl_xor(a, 16); b += __shfl_xor(b, 16);
            a += __shfl_xor(a, 32); b += __shfl_xor(b, 32);
            if ((lane >> 4) == 0) {
                int col = bn + wc * 64 + n * 16 + fr;
                atomicAdd(&extra[col], a);
                atomicAdd(&extra[256 + col], b);
            }
        }
    }
}

// ---------------- head GEMM: 256x128 tile, BK=64, 8 waves ----------------
// T-tile = relu(Hcat[256 x 768] @ lin1t^T [128 x 768] + b); then
// part[coltile][row][0..1] = T-tile @ w2-slice.  Atomic-free (LDS combine).

__global__ __launch_bounds__(512) void gemm_head(
    const ushort* __restrict__ A,    // Hcat [MP x 768]
    const ushort* __restrict__ Bt,   // lin1t [768 x 768]
    const float* __restrict__ bias,  // lin1_b [768]
    const float* __restrict__ w2,    // lin2_W [768 x 2]
    float* __restrict__ part,        // [6][MP][2]
    int K, int MP) {
    __shared__ ushort As[256 * 64];     // 32 KB
    __shared__ ushort Bs[128 * 64];     // 16 KB
    __shared__ float sm_part[256][2];   // 2 KB
    const int tid = threadIdx.x;

    // XCD-bijective swizzle (nwg = 6*196 = 1176, %8==0)
    const int gx = gridDim.x;
    const int nwg = gx * gridDim.y;
    const int flat = blockIdx.y * gx + blockIdx.x;
    const int q = nwg >> 3, r = nwg & 7;
    const int xcd = flat & 7, loc = flat >> 3;
    const int wg = (xcd < r ? xcd * (q + 1) : r * (q + 1) + (xcd - r) * q) + loc;
    const int bm = (wg / gx) * 256;
    const int bn = (wg % gx) * 128;
    const int coltile = wg % gx;

    const int lane = tid & 63;
    const int wid = tid >> 6;        // 0..7
    const int wr = wid >> 1;         // 0..3 (64-row band)
    const int wc = wid & 1;          // 0..1 (64-col half)

    sm_part[tid >> 1][tid & 1] = 0.f;

    f32x4 acc[4][4] = {};

    const int grow = tid >> 3;           // 0..63
    const int gcol = (tid & 7) * 8;      // element offset (16B chunks)
    const int wbase = (tid & ~63) * 8;   // wave-uniform LDS elem base
    const int kko = (lane >> 4) * 8;
    const int fr = lane & 15;

    for (int k0 = 0; k0 < K; k0 += 64) {
        #pragma unroll
        for (int c = 0; c < 4; ++c)
            gload_lds16(A + (size_t)(bm + c * 64 + grow) * K + k0 + gcol,
                        &As[c * 4096 + wbase]);
        #pragma unroll
        for (int c = 0; c < 2; ++c)
            gload_lds16(Bt + (size_t)(bn + c * 64 + grow) * K + k0 + gcol,
                        &Bs[c * 4096 + wbase]);
        __syncthreads();
        #pragma unroll
        for (int ksub = 0; ksub < 2; ++ksub) {
            short8 af[4], bf[4];
            #pragma unroll
            for (int m = 0; m < 4; ++m)
                af[m] = *(const short8*)&As[(wr * 64 + m * 16 + fr) * 64 + ksub * 32 + kko];
            #pragma unroll
            for (int n = 0; n < 4; ++n)
                bf[n] = *(const short8*)&Bs[(wc * 64 + n * 16 + fr) * 64 + ksub * 32 + kko];
            #pragma unroll
            for (int m = 0; m < 4; ++m)
                #pragma unroll
                for (int n = 0; n < 4; ++n)
                    acc[m][n] = __builtin_amdgcn_mfma_f32_16x16x32_bf16(af[m], bf[n], acc[m][n], 0, 0, 0);
        }
        __syncthreads();
    }

    // epilogue: relu(v+bias) dot w2 -> reduce over fr -> LDS combine (wc pair)
    #pragma unroll
    for (int m = 0; m < 4; ++m) {
        #pragma unroll
        for (int rr = 0; rr < 4; ++rr) {
            float o0 = 0.f, o1 = 0.f;
            #pragma unroll
            for (int n = 0; n < 4; ++n) {
                int col = bn + wc * 64 + n * 16 + fr;
                float v = fmaxf(acc[m][n][rr] + bias[col], 0.f);
                o0 = fmaf(v, w2[col * 2 + 0], o0);
                o1 = fmaf(v, w2[col * 2 + 1], o1);
            }
            o0 += __shfl_xor(o0, 1); o1 += __shfl_xor(o1, 1);
            o0 += __shfl_xor(o0, 2); o1 += __shfl_xor(o1, 2);
            o0 += __shfl_xor(o0, 4); o1 += __shfl_xor(o1, 4);
            o0 += __shfl_xor(o0, 8); o1 += __shfl_xor(o1, 8);
            if (fr == 0) {
                int lrow = wr * 64 + m * 16 + (lane >> 4) * 4 + rr;
                atomicAdd(&sm_part[lrow][0], o0);
                atomicAdd(&sm_part[lrow][1], o1);
            }
        }
    }
    __syncthreads();
    // 512 threads store 256 rows x 2 comps
    {
        int lrow = tid >> 1, comp = tid & 1;
        part[((size_t)coltile * MP + bm + lrow) * 2 + comp] = sm_part[lrow][comp];
    }
}

// ---------------- BN apply (normalize + relu, write bf16) ----------------

__global__ void bn_apply(const float* __restrict__ h, const float* __restrict__ sums,
                         const float* __restrict__ g, const float* __restrict__ be,
                         ushort* __restrict__ outb, int Nrows) {
    int total = Nrows * 128;
    float inv = 1.0f / (float)Nrows;
    for (int idx = blockIdx.x * blockDim.x + threadIdx.x; idx < total;
         idx += gridDim.x * blockDim.x) {
        int row = idx >> 7;
        int cp = (idx & 127) * 2;
        float2 v = *(const float2*)(h + (size_t)row * 256 + cp);
        float mu0 = sums[cp] * inv,     mu1 = sums[cp + 1] * inv;
        float va0 = sums[256 + cp] * inv - mu0 * mu0;
        float va1 = sums[257 + cp] * inv - mu1 * mu1;
        float o0 = fmaxf((v.x - mu0) * rsqrtf(va0 + 1e-5f) * g[cp]     + be[cp],     0.f);
        float o1 = fmaxf((v.y - mu1) * rsqrtf(va1 + 1e-5f) * g[cp + 1] + be[cp + 1], 0.f);
        *(uint*)(outb + (size_t)row * 256 + cp) = pack_bf16(o0, o1);
    }
}

// ---------------- finalize: sum 6 partials + bias + softmax ----------------

__global__ void finalize6(const float* __restrict__ part, const float* __restrict__ b2,
                          float* __restrict__ out, int Nrows, int MP) {
    int i = blockIdx.x * blockDim.x + threadIdx.x;
    if (i >= Nrows) return;
    float h0 = b2[0], h1 = b2[1];
    #pragma unroll
    for (int c = 0; c < 6; ++c) {
        h0 += part[((size_t)c * MP + i) * 2 + 0];
        h1 += part[((size_t)c * MP + i) * 2 + 1];
    }
    out[2 * i] = h0;
    out[2 * i + 1] = h1;
    float m = fmaxf(h0, h1);
    float e0 = expf(h0 - m), e1 = expf(h1 - m);
    float s = e0 + e1;
    out[(size_t)2 * Nrows + 2 * i] = e0 / s;
    out[(size_t)2 * Nrows + 2 * i + 1] = e1 / s;
}

// ---------------------------------------------------------------------------

extern "C" void kernel_launch(void* const* d_in, const int* in_sizes, int n_in,
                              void* d_out, int out_size, void* d_ws, size_t ws_size,
                              hipStream_t stream) {
    const int N = in_sizes[0] / GIN_N_FEAT_IN;     // 50000
    const int E = in_sizes[1] / 2;                 // 800000
    const int MP = M_PAD_ROWS;
    const int nchunks = (N + 255) / 256;           // 196

    const float* x  = (const float*)d_in[0];
    const int*   ei = (const int*)d_in[1];
    const float* cW1[3] = {(const float*)d_in[2],  (const float*)d_in[8],  (const float*)d_in[14]};
    const float* cb1[3] = {(const float*)d_in[3],  (const float*)d_in[9],  (const float*)d_in[15]};
    const float* cg [3] = {(const float*)d_in[4],  (const float*)d_in[10], (const float*)d_in[16]};
    const float* cbe[3] = {(const float*)d_in[5],  (const float*)d_in[11], (const float*)d_in[17]};
    const float* cW2[3] = {(const float*)d_in[6],  (const float*)d_in[12], (const float*)d_in[18]};
    const float* cb2[3] = {(const float*)d_in[7],  (const float*)d_in[13], (const float*)d_in[19]};
    const float* lin1_W = (const float*)d_in[20];  // [768,768]
    const float* lin1_b = (const float*)d_in[21];
    const float* lin2_W = (const float*)d_in[22];  // [768,2]
    const float* lin2_b = (const float*)d_in[23];
    float* out = (float*)d_out;

    // ---- workspace carve-up (row buffers padded to MP rows) ----
    char* ws = (char*)d_ws;
    size_t off = 0;
    auto carve = [&](size_t bytes) {
        void* p = ws + off;
        off += (bytes + 255) & ~(size_t)255;
        return p;
    };
    ushort* Hcat   = (ushort*)carve((size_t)MP * 768 * 2);   // bf16 h1|h2|h3
    float*  hlin   = (float*) carve((size_t)MP * 256 * 4);   // f32 gemm1 out
    ushort* hlin_b = (ushort*)carve((size_t)MP * 256 * 2);   // bf16 after BN
    ushort* hpre   = (ushort*)carve((size_t)MP * 256 * 2);   // bf16 agg out
    ushort* xb     = (ushort*)carve((size_t)MP * 128 * 2);   // bf16 input
    ushort* w1t[3] = {(ushort*)carve(256 * 256 * 2), (ushort*)carve(256 * 256 * 2),
                      (ushort*)carve(256 * 256 * 2)};
    ushort* w2t[3] = {(ushort*)carve(256 * 256 * 2), (ushort*)carve(256 * 256 * 2),
                      (ushort*)carve(256 * 256 * 2)};
    ushort* lin1t  = (ushort*)carve((size_t)768 * 768 * 2);
    int*   row_st  = (int*)carve((size_t)(N + 1) * 4);
    int*   cursor  = (int*)carve((size_t)N * 4);
    int*   perm    = (int*)carve((size_t)E * 4);
    int*   csums   = (int*)carve(256 * 4);
    float* bnsums  = (float*)carve(512 * 4);
    float* part    = (float*)carve((size_t)6 * MP * 2 * 4);
    (void)ws_size;

    // ---- conversions ----
    cvt_f32_bf16<<<1024, 256, 0, stream>>>(x, xb, N * 64);
    WPrep wp;
    wp.src[0] = cW1[0]; wp.dst[0] = w1t[0]; wp.R[0] = 128; wp.C[0] = 256;
    wp.src[1] = cW1[1]; wp.dst[1] = w1t[1]; wp.R[1] = 256; wp.C[1] = 256;
    wp.src[2] = cW1[2]; wp.dst[2] = w1t[2]; wp.R[2] = 256; wp.C[2] = 256;
    wp.src[3] = cW2[0]; wp.dst[3] = w2t[0]; wp.R[3] = 256; wp.C[3] = 256;
    wp.src[4] = cW2[1]; wp.dst[4] = w2t[1]; wp.R[4] = 256; wp.C[4] = 256;
    wp.src[5] = cW2[2]; wp.dst[5] = w2t[2]; wp.R[5] = 256; wp.C[5] = 256;
    wp.src[6] = lin1_W; wp.dst[6] = lin1t;  wp.R[6] = 768; wp.C[6] = 768;
    prep_weights<<<dim3(576, 7), 256, 0, stream>>>(wp);

    // ---- CSR build (3-stage parallel scan) ----
    hipMemsetAsync(cursor, 0, (size_t)N * 4, stream);
    count_kernel<<<1024, 256, 0, stream>>>(ei, cursor, E);
    scan_chunk<<<nchunks, 256, 0, stream>>>(cursor, row_st, csums, N);
    scan_tops<<<1, 256, 0, stream>>>(csums, row_st, nchunks, N, E);
    scan_add<<<nchunks, 256, 0, stream>>>(row_st, cursor, csums, N);
    scatter_kernel<<<1024, 256, 0, stream>>>(ei, cursor, perm, E);

    const dim3 ggrid(2, MP / 128);       // conv GEMMs (784 WGs, %8==0)
    const int aggblocks = (N + 3) / 4;   // wave per node

    // ---- 3 GIN conv layers ----
    for (int L = 0; L < 3; ++L) {
        if (L == 0)
            agg2<128><<<aggblocks, 256, 0, stream>>>(xb, 128, row_st, perm, hpre, N);
        else
            agg2<256><<<aggblocks, 256, 0, stream>>>(Hcat + (size_t)(L - 1) * 256, 768,
                                                     row_st, perm, hpre, N);

        // GEMM1 + fused BN stats
        hipMemsetAsync(bnsums, 0, 512 * 4, stream);
        gemm_mfma<0><<<ggrid, 256, 0, stream>>>(
            hpre, w1t[L], cb1[L], hlin, 256, (L == 0) ? 128 : 256, bnsums, N);

        bn_apply<<<2048, 256, 0, stream>>>(hlin, bnsums, cg[L], cbe[L], hlin_b, N);

        // GEMM2 -> Hcat column block L (bf16, ldc=768)
        gemm_mfma<1><<<ggrid, 256, 0, stream>>>(
            hlin_b, w2t[L], cb2[L], (void*)(Hcat + (size_t)L * 256), 768, 256,
            nullptr, 0);
    }

    // ---- head: 256x128-tile fused gemm (lin1+relu+lin2 partials) ----
    gemm_head<<<dim3(6, MP / 256), 512, 0, stream>>>(
        Hcat, lin1t, lin1_b, lin2_W, part, 768, MP);

    finalize6<<<(N + 255) / 256, 256, 0, stream>>>(part, lin2_b, out, N, MP);
}

// Round 7
// 677.112 us; speedup vs baseline: 3.4948x; 1.0145x over previous
//
#include <hip/hip_runtime.h>
#include <hip/hip_bf16.h>

// ---------------------------------------------------------------------------
// GIN on MI355X: bf16 MFMA GEMMs, all with:
//  - T2 LDS XOR-swizzle (2-way residual conflicts), legal with global_load_lds
//    via pre-swizzled GLOBAL source + swizzled ds_read (both-sides, rule #21)
//  - T3-minimum prefetch double-buffer (stage t+1 before compute t)
// Conv: 128x128/BK=32, fused BN-stats. Head: 256x128/BK=32, fused relu+lin2.
// ---------------------------------------------------------------------------

#define GIN_N_FEAT_IN 128
#define GIN_H 256
#define M_PAD_ROWS 50176   // 50000 padded to 256 (head tile height)

typedef short short8 __attribute__((ext_vector_type(8)));
typedef float f32x4 __attribute__((ext_vector_type(4)));

__device__ inline ushort f32_to_bf16(float f) {
    union { float f; uint u; } x; x.f = f;
    uint r = x.u + 0x7fff + ((x.u >> 16) & 1);
    return (ushort)(r >> 16);
}
__device__ inline float bf16_to_f32(uint h) {
    union { uint u; float f; } x; x.u = h << 16;
    return x.f;
}
__device__ inline uint pack_bf16(float lo, float hi) {
    return (uint)f32_to_bf16(lo) | ((uint)f32_to_bf16(hi) << 16);
}

__device__ inline void gload_lds16(const ushort* g, ushort* l) {
    __builtin_amdgcn_global_load_lds(
        (const __attribute__((address_space(1))) void*)g,
        (__attribute__((address_space(3))) void*)l, 16, 0, 0);
}

// ---------------- conversions ----------------

__global__ void cvt_f32_bf16(const float* __restrict__ in, ushort* __restrict__ out, int npairs) {
    for (int i = blockIdx.x * blockDim.x + threadIdx.x; i < npairs; i += gridDim.x * blockDim.x) {
        float2 v = ((const float2*)in)[i];
        ((uint*)out)[i] = pack_bf16(v.x, v.y);
    }
}

// all weight transposes in one dispatch: dst[c][r] = bf16(src[r][c])
struct WPrep {
    const float* src[7];
    ushort* dst[7];
    int R[7];
    int C[7];
};

__global__ void prep_weights(WPrep p) {
    int which = blockIdx.y;
    int R = p.R[which], C = p.C[which];
    int total = R * C;
    const float* src = p.src[which];
    ushort* dst = p.dst[which];
    for (int idx = blockIdx.x * blockDim.x + threadIdx.x; idx < total;
         idx += gridDim.x * blockDim.x) {
        int r = idx / C, c = idx - r * C;
        dst[(size_t)c * R + r] = f32_to_bf16(src[idx]);
    }
}

// ---------------- CSR build ----------------

__global__ void count_kernel(const int* __restrict__ ei, int* __restrict__ deg, int E) {
    for (int e = blockIdx.x * blockDim.x + threadIdx.x; e < E; e += gridDim.x * blockDim.x) {
        atomicAdd(&deg[ei[E + e]], 1);   // dst = ei[1][e]
    }
}

__global__ void scan_chunk(const int* __restrict__ deg, int* __restrict__ row_start,
                           int* __restrict__ chunk_sums, int N) {
    __shared__ int sm[256];
    int tid = threadIdx.x;
    int idx = blockIdx.x * 256 + tid;
    int v = (idx < N) ? deg[idx] : 0;
    sm[tid] = v;
    __syncthreads();
    #pragma unroll
    for (int off = 1; off < 256; off <<= 1) {
        int t = (tid >= off) ? sm[tid - off] : 0;
        __syncthreads();
        sm[tid] += t;
        __syncthreads();
    }
    if (idx < N) row_start[idx] = sm[tid] - v;
    if (tid == 255) chunk_sums[blockIdx.x] = sm[255];
}

__global__ void scan_tops(int* __restrict__ chunk_sums, int* __restrict__ row_start,
                          int nchunks, int N, int E) {
    __shared__ int sm[256];
    int tid = threadIdx.x;
    int v = (tid < nchunks) ? chunk_sums[tid] : 0;
    sm[tid] = v;
    __syncthreads();
    #pragma unroll
    for (int off = 1; off < 256; off <<= 1) {
        int t = (tid >= off) ? sm[tid - off] : 0;
        __syncthreads();
        sm[tid] += t;
        __syncthreads();
    }
    if (tid < nchunks) chunk_sums[tid] = sm[tid] - v;
    if (tid == 0) row_start[N] = E;
}

__global__ void scan_add(int* __restrict__ row_start, int* __restrict__ cursor,
                         const int* __restrict__ chunk_sums, int N) {
    int idx = blockIdx.x * 256 + threadIdx.x;
    if (idx < N) {
        int v = row_start[idx] + chunk_sums[blockIdx.x];
        row_start[idx] = v;
        cursor[idx] = v;
    }
}

__global__ void scatter_kernel(const int* __restrict__ ei, int* __restrict__ cursor,
                               int* __restrict__ perm, int E) {
    for (int e = blockIdx.x * blockDim.x + threadIdx.x; e < E; e += gridDim.x * blockDim.x) {
        int d = ei[E + e];
        int pos = atomicAdd(&cursor[d], 1);
        perm[pos] = ei[e];
    }
}

// ---------------- aggregation: wave-per-node, unroll-4 ILP ----------------

template <int W>
__global__ void agg2(const ushort* __restrict__ xsrc, int stride,
                     const int* __restrict__ row_start, const int* __restrict__ perm,
                     ushort* __restrict__ out, int N) {
    constexpr int PL = W / 64;                 // bf16 per lane: 2 or 4
    int node = blockIdx.x * 4 + (threadIdx.x >> 6);
    if (node >= N) return;
    const int lane = threadIdx.x & 63;
    const size_t loff = (size_t)lane * PL;

    float af[PL];
    {
        const ushort* p = xsrc + (size_t)node * stride + loff;
        if constexpr (W == 256) {
            uint2 v = *(const uint2*)p;
            af[0] = bf16_to_f32(v.x & 0xffffu); af[1] = bf16_to_f32(v.x >> 16);
            af[2] = bf16_to_f32(v.y & 0xffffu); af[3] = bf16_to_f32(v.y >> 16);
        } else {
            uint v = *(const uint*)p;
            af[0] = bf16_to_f32(v & 0xffffu); af[1] = bf16_to_f32(v >> 16);
        }
    }
    const int s = row_start[node], e = row_start[node + 1];
    int j = s;
    for (; j + 4 <= e; j += 4) {
        int n0 = perm[j], n1 = perm[j + 1], n2 = perm[j + 2], n3 = perm[j + 3];
        if constexpr (W == 256) {
            uint2 w0 = *(const uint2*)(xsrc + (size_t)n0 * stride + loff);
            uint2 w1 = *(const uint2*)(xsrc + (size_t)n1 * stride + loff);
            uint2 w2 = *(const uint2*)(xsrc + (size_t)n2 * stride + loff);
            uint2 w3 = *(const uint2*)(xsrc + (size_t)n3 * stride + loff);
            af[0] += bf16_to_f32(w0.x & 0xffffu) + bf16_to_f32(w1.x & 0xffffu)
                   + bf16_to_f32(w2.x & 0xffffu) + bf16_to_f32(w3.x & 0xffffu);
            af[1] += bf16_to_f32(w0.x >> 16) + bf16_to_f32(w1.x >> 16)
                   + bf16_to_f32(w2.x >> 16) + bf16_to_f32(w3.x >> 16);
            af[2] += bf16_to_f32(w0.y & 0xffffu) + bf16_to_f32(w1.y & 0xffffu)
                   + bf16_to_f32(w2.y & 0xffffu) + bf16_to_f32(w3.y & 0xffffu);
            af[3] += bf16_to_f32(w0.y >> 16) + bf16_to_f32(w1.y >> 16)
                   + bf16_to_f32(w2.y >> 16) + bf16_to_f32(w3.y >> 16);
        } else {
            uint w0 = *(const uint*)(xsrc + (size_t)n0 * stride + loff);
            uint w1 = *(const uint*)(xsrc + (size_t)n1 * stride + loff);
            uint w2 = *(const uint*)(xsrc + (size_t)n2 * stride + loff);
            uint w3 = *(const uint*)(xsrc + (size_t)n3 * stride + loff);
            af[0] += bf16_to_f32(w0 & 0xffffu) + bf16_to_f32(w1 & 0xffffu)
                   + bf16_to_f32(w2 & 0xffffu) + bf16_to_f32(w3 & 0xffffu);
            af[1] += bf16_to_f32(w0 >> 16) + bf16_to_f32(w1 >> 16)
                   + bf16_to_f32(w2 >> 16) + bf16_to_f32(w3 >> 16);
        }
    }
    for (; j < e; ++j) {
        int sn = perm[j];
        const ushort* p = xsrc + (size_t)sn * stride + loff;
        if constexpr (W == 256) {
            uint2 w = *(const uint2*)p;
            af[0] += bf16_to_f32(w.x & 0xffffu); af[1] += bf16_to_f32(w.x >> 16);
            af[2] += bf16_to_f32(w.y & 0xffffu); af[3] += bf16_to_f32(w.y >> 16);
        } else {
            uint w = *(const uint*)p;
            af[0] += bf16_to_f32(w & 0xffffu); af[1] += bf16_to_f32(w >> 16);
        }
    }
    ushort* po = out + (size_t)node * W + loff;
    if constexpr (W == 256) {
        uint2 o; o.x = pack_bf16(af[0], af[1]); o.y = pack_bf16(af[2], af[3]);
        *(uint2*)po = o;
    } else {
        *(uint*)po = pack_bf16(af[0], af[1]);
    }
}

// ---------------- conv bf16 MFMA GEMM: 128x128, BK=32, dbuf + swizzle --------
// Rows are 32 ushort (64 B) = 4 x 16B chunks. Stored chunk s = c ^ ((row>>1)&3)
// -> within each 16-lane ds_read quarter all 8 bank slots distinct (2-way, free).
// Write side realized by swizzling the per-lane GLOBAL column (LDS stays linear
// for global_load_lds). MODE 0: f32 store + fused BN stats; MODE 1: bf16+relu.

template <int MODE>
__global__ __launch_bounds__(256) void gemm_mfma(
    const ushort* __restrict__ A, const ushort* __restrict__ Bt,
    const float* __restrict__ bias, void* __restrict__ Cout,
    int ldc, int K, float* __restrict__ extra, int Nvalid) {
    __shared__ ushort As[2][128 * 32];
    __shared__ ushort Bs[2][128 * 32];
    const int tid = threadIdx.x;

    // XCD-bijective chunked swizzle (m204)
    const int gx = gridDim.x;
    const int nwg = gx * gridDim.y;
    const int flat = blockIdx.y * gx + blockIdx.x;
    const int q = nwg >> 3, r = nwg & 7;
    const int xcd = flat & 7, loc = flat >> 3;
    const int wg = (xcd < r ? xcd * (q + 1) : r * (q + 1) + (xcd - r) * q) + loc;
    const int bm = (wg / gx) * 128;
    const int bn = (wg % gx) * 128;

    const int lane = tid & 63;
    const int wid = tid >> 6;
    const int wr = wid >> 1, wc = wid & 1;

    f32x4 acc[4][4] = {};

    // staging: thread t -> row t>>2 (per 64-row half), stored chunk t&3.
    // global column chunk = (t&3) ^ ((t>>3)&3)  [inverse of stored swizzle]
    const int arow = tid >> 2;
    const int gcol = ((tid & 3) ^ ((tid >> 3) & 3)) * 8;
    const ushort* Ag0 = A + (size_t)(bm + arow) * K + gcol;
    const ushort* Ag1 = A + (size_t)(bm + 64 + arow) * K + gcol;
    const ushort* Bg0 = Bt + (size_t)(bn + arow) * K + gcol;
    const ushort* Bg1 = Bt + (size_t)(bn + 64 + arow) * K + gcol;
    const int wofs = (tid & ~63) * 8;   // wave-uniform LDS base, HW adds lane*16B

    const int fr = lane & 15;
    // read: logical chunk = lane>>4; stored = chunk ^ ((row>>1)&3), row%16==fr
    const int rchunk = ((lane >> 4) ^ ((fr >> 1) & 3)) * 8;

    const int NT = K >> 5;

    // prologue: stage tile 0 into buf 0
    {
        ushort* a = As[0]; ushort* b = Bs[0];
        gload_lds16(Ag0, a + wofs);
        gload_lds16(Ag1, a + 2048 + wofs);
        gload_lds16(Bg0, b + wofs);
        gload_lds16(Bg1, b + 2048 + wofs);
    }
    __syncthreads();

    for (int it = 0; it < NT; ++it) {
        if (it + 1 < NT) {                      // prefetch next tile
            const int k0 = (it + 1) << 5;
            ushort* a = As[(it + 1) & 1]; ushort* b = Bs[(it + 1) & 1];
            gload_lds16(Ag0 + k0, a + wofs);
            gload_lds16(Ag1 + k0, a + 2048 + wofs);
            gload_lds16(Bg0 + k0, b + wofs);
            gload_lds16(Bg1 + k0, b + 2048 + wofs);
        }
        const ushort* as = As[it & 1];
        const ushort* bs = Bs[it & 1];
        short8 af[4], bf[4];
        #pragma unroll
        for (int m = 0; m < 4; ++m)
            af[m] = *(const short8*)&as[(wr * 64 + m * 16 + fr) * 32 + rchunk];
        #pragma unroll
        for (int n = 0; n < 4; ++n)
            bf[n] = *(const short8*)&bs[(wc * 64 + n * 16 + fr) * 32 + rchunk];
        #pragma unroll
        for (int m = 0; m < 4; ++m)
            #pragma unroll
            for (int n = 0; n < 4; ++n)
                acc[m][n] = __builtin_amdgcn_mfma_f32_16x16x32_bf16(af[m], bf[n], acc[m][n], 0, 0, 0);
        __syncthreads();   // next tile staged + this tile's reads done
    }

    // epilogue: C/D layout col=lane&15, row=(lane>>4)*4+reg
    float s1[4], s2[4];
    if constexpr (MODE == 0) {
        #pragma unroll
        for (int n = 0; n < 4; ++n) { s1[n] = 0.f; s2[n] = 0.f; }
    }
    #pragma unroll
    for (int n = 0; n < 4; ++n) {
        const int col = bn + wc * 64 + n * 16 + fr;
        const float bv = bias[col];
        #pragma unroll
        for (int m = 0; m < 4; ++m) {
            const int row0 = bm + wr * 64 + m * 16 + (lane >> 4) * 4;
            #pragma unroll
            for (int rr = 0; rr < 4; ++rr) {
                float v = acc[m][n][rr] + bv;
                if constexpr (MODE == 1) {
                    v = fmaxf(v, 0.f);
                    ((ushort*)Cout)[(size_t)(row0 + rr) * ldc + col] = f32_to_bf16(v);
                } else {
                    ((float*)Cout)[(size_t)(row0 + rr) * ldc + col] = v;
                    if (row0 + rr < Nvalid) { s1[n] += v; s2[n] += v * v; }
                }
            }
        }
    }
    if constexpr (MODE == 0) {
        #pragma unroll
        for (int n = 0; n < 4; ++n) {
            float a = s1[n], b = s2[n];
            a += __shfl_xor(a, 16); b += __shfl_xor(b, 16);
            a += __shfl_xor(a, 32); b += __shfl_xor(b, 32);
            if ((lane >> 4) == 0) {
                int col = bn + wc * 64 + n * 16 + fr;
                atomicAdd(&extra[col], a);
                atomicAdd(&extra[256 + col], b);
            }
        }
    }
}

// ---------------- head GEMM: 256x128, BK=32, 8 waves, dbuf + swizzle ---------
// T-tile = relu(Hcat[256x768] @ lin1t^T[128x768] + b); fused lin2 dot ->
// part[coltile][row][0..1].  Atomic-free global (LDS combine).

__global__ __launch_bounds__(512) void gemm_head(
    const ushort* __restrict__ A,    // Hcat [MP x 768]
    const ushort* __restrict__ Bt,   // lin1t [768 x 768]
    const float* __restrict__ bias,  // lin1_b [768]
    const float* __restrict__ w2,    // lin2_W [768 x 2]
    float* __restrict__ part,        // [6][MP][2]
    int K, int MP) {
    __shared__ ushort As[2][256 * 32];  // 32 KB
    __shared__ ushort Bs[2][128 * 32];  // 16 KB
    __shared__ float sm_part[256][2];   // 2 KB   -> 50 KB total, 3 blocks/CU
    const int tid = threadIdx.x;

    // XCD-bijective swizzle (nwg = 6*196 = 1176, %8==0)
    const int gx = gridDim.x;
    const int nwg = gx * gridDim.y;
    const int flat = blockIdx.y * gx + blockIdx.x;
    const int q = nwg >> 3, r = nwg & 7;
    const int xcd = flat & 7, loc = flat >> 3;
    const int wg = (xcd < r ? xcd * (q + 1) : r * (q + 1) + (xcd - r) * q) + loc;
    const int bm = (wg / gx) * 256;
    const int bn = (wg % gx) * 128;
    const int coltile = wg % gx;

    const int lane = tid & 63;
    const int wid = tid >> 6;        // 0..7
    const int wr = wid >> 1;         // 0..3 (64-row band of 256)
    const int wc = wid & 1;          // 0..1 (64-col half of 128)

    sm_part[tid >> 1][tid & 1] = 0.f;

    f32x4 acc[4][4] = {};

    // staging: thread t -> row t>>2 (0..127 per section), stored chunk t&3;
    // global column chunk = (t&3) ^ ((t>>3)&3)
    const int arow = tid >> 2;
    const int gcol = ((tid & 3) ^ ((tid >> 3) & 3)) * 8;
    const ushort* Ag0 = A + (size_t)(bm + arow) * K + gcol;         // rows 0..127
    const ushort* Ag1 = A + (size_t)(bm + 128 + arow) * K + gcol;   // rows 128..255
    const ushort* Bg0 = Bt + (size_t)(bn + arow) * K + gcol;        // 128 rows
    const int wofs = (tid & ~63) * 8;

    const int fr = lane & 15;
    const int rchunk = ((lane >> 4) ^ ((fr >> 1) & 3)) * 8;

    const int NT = K >> 5;   // 24

    {
        ushort* a = As[0]; ushort* b = Bs[0];
        gload_lds16(Ag0, a + wofs);
        gload_lds16(Ag1, a + 4096 + wofs);
        gload_lds16(Bg0, b + wofs);
    }
    __syncthreads();

    for (int it = 0; it < NT; ++it) {
        if (it + 1 < NT) {
            const int k0 = (it + 1) << 5;
            ushort* a = As[(it + 1) & 1]; ushort* b = Bs[(it + 1) & 1];
            gload_lds16(Ag0 + k0, a + wofs);
            gload_lds16(Ag1 + k0, a + 4096 + wofs);
            gload_lds16(Bg0 + k0, b + wofs);
        }
        const ushort* as = As[it & 1];
        const ushort* bs = Bs[it & 1];
        short8 af[4], bf[4];
        #pragma unroll
        for (int m = 0; m < 4; ++m)
            af[m] = *(const short8*)&as[(wr * 64 + m * 16 + fr) * 32 + rchunk];
        #pragma unroll
        for (int n = 0; n < 4; ++n)
            bf[n] = *(const short8*)&bs[(wc * 64 + n * 16 + fr) * 32 + rchunk];
        #pragma unroll
        for (int m = 0; m < 4; ++m)
            #pragma unroll
            for (int n = 0; n < 4; ++n)
                acc[m][n] = __builtin_amdgcn_mfma_f32_16x16x32_bf16(af[m], bf[n], acc[m][n], 0, 0, 0);
        __syncthreads();
    }

    // epilogue: relu(v+bias) dot w2 -> reduce over fr -> LDS combine
    #pragma unroll
    for (int m = 0; m < 4; ++m) {
        #pragma unroll
        for (int rr = 0; rr < 4; ++rr) {
            float o0 = 0.f, o1 = 0.f;
            #pragma unroll
            for (int n = 0; n < 4; ++n) {
                int col = bn + wc * 64 + n * 16 + fr;
                float v = fmaxf(acc[m][n][rr] + bias[col], 0.f);
                o0 = fmaf(v, w2[col * 2 + 0], o0);
                o1 = fmaf(v, w2[col * 2 + 1], o1);
            }
            o0 += __shfl_xor(o0, 1); o1 += __shfl_xor(o1, 1);
            o0 += __shfl_xor(o0, 2); o1 += __shfl_xor(o1, 2);
            o0 += __shfl_xor(o0, 4); o1 += __shfl_xor(o1, 4);
            o0 += __shfl_xor(o0, 8); o1 += __shfl_xor(o1, 8);
            if (fr == 0) {
                int lrow = wr * 64 + m * 16 + (lane >> 4) * 4 + rr;
                atomicAdd(&sm_part[lrow][0], o0);
                atomicAdd(&sm_part[lrow][1], o1);
            }
        }
    }
    __syncthreads();
    {
        int lrow = tid >> 1, comp = tid & 1;
        part[((size_t)coltile * MP + bm + lrow) * 2 + comp] = sm_part[lrow][comp];
    }
}

// ---------------- BN apply (normalize + relu, write bf16) ----------------

__global__ void bn_apply(const float* __restrict__ h, const float* __restrict__ sums,
                         const float* __restrict__ g, const float* __restrict__ be,
                         ushort* __restrict__ outb, int Nrows) {
    int total = Nrows * 128;
    float inv = 1.0f / (float)Nrows;
    for (int idx = blockIdx.x * blockDim.x + threadIdx.x; idx < total;
         idx += gridDim.x * blockDim.x) {
        int row = idx >> 7;
        int cp = (idx & 127) * 2;
        float2 v = *(const float2*)(h + (size_t)row * 256 + cp);
        float mu0 = sums[cp] * inv,     mu1 = sums[cp + 1] * inv;
        float va0 = sums[256 + cp] * inv - mu0 * mu0;
        float va1 = sums[257 + cp] * inv - mu1 * mu1;
        float o0 = fmaxf((v.x - mu0) * rsqrtf(va0 + 1e-5f) * g[cp]     + be[cp],     0.f);
        float o1 = fmaxf((v.y - mu1) * rsqrtf(va1 + 1e-5f) * g[cp + 1] + be[cp + 1], 0.f);
        *(uint*)(outb + (size_t)row * 256 + cp) = pack_bf16(o0, o1);
    }
}

// ---------------- finalize: sum 6 partials + bias + softmax ----------------

__global__ void finalize6(const float* __restrict__ part, const float* __restrict__ b2,
                          float* __restrict__ out, int Nrows, int MP) {
    int i = blockIdx.x * blockDim.x + threadIdx.x;
    if (i >= Nrows) return;
    float h0 = b2[0], h1 = b2[1];
    #pragma unroll
    for (int c = 0; c < 6; ++c) {
        h0 += part[((size_t)c * MP + i) * 2 + 0];
        h1 += part[((size_t)c * MP + i) * 2 + 1];
    }
    out[2 * i] = h0;
    out[2 * i + 1] = h1;
    float m = fmaxf(h0, h1);
    float e0 = expf(h0 - m), e1 = expf(h1 - m);
    float s = e0 + e1;
    out[(size_t)2 * Nrows + 2 * i] = e0 / s;
    out[(size_t)2 * Nrows + 2 * i + 1] = e1 / s;
}

// ---------------------------------------------------------------------------

extern "C" void kernel_launch(void* const* d_in, const int* in_sizes, int n_in,
                              void* d_out, int out_size, void* d_ws, size_t ws_size,
                              hipStream_t stream) {
    const int N = in_sizes[0] / GIN_N_FEAT_IN;     // 50000
    const int E = in_sizes[1] / 2;                 // 800000
    const int MP = M_PAD_ROWS;
    const int nchunks = (N + 255) / 256;           // 196

    const float* x  = (const float*)d_in[0];
    const int*   ei = (const int*)d_in[1];
    const float* cW1[3] = {(const float*)d_in[2],  (const float*)d_in[8],  (const float*)d_in[14]};
    const float* cb1[3] = {(const float*)d_in[3],  (const float*)d_in[9],  (const float*)d_in[15]};
    const float* cg [3] = {(const float*)d_in[4],  (const float*)d_in[10], (const float*)d_in[16]};
    const float* cbe[3] = {(const float*)d_in[5],  (const float*)d_in[11], (const float*)d_in[17]};
    const float* cW2[3] = {(const float*)d_in[6],  (const float*)d_in[12], (const float*)d_in[18]};
    const float* cb2[3] = {(const float*)d_in[7],  (const float*)d_in[13], (const float*)d_in[19]};
    const float* lin1_W = (const float*)d_in[20];  // [768,768]
    const float* lin1_b = (const float*)d_in[21];
    const float* lin2_W = (const float*)d_in[22];  // [768,2]
    const float* lin2_b = (const float*)d_in[23];
    float* out = (float*)d_out;

    // ---- workspace carve-up (row buffers padded to MP rows) ----
    char* ws = (char*)d_ws;
    size_t off = 0;
    auto carve = [&](size_t bytes) {
        void* p = ws + off;
        off += (bytes + 255) & ~(size_t)255;
        return p;
    };
    ushort* Hcat   = (ushort*)carve((size_t)MP * 768 * 2);   // bf16 h1|h2|h3
    float*  hlin   = (float*) carve((size_t)MP * 256 * 4);   // f32 gemm1 out
    ushort* hlin_b = (ushort*)carve((size_t)MP * 256 * 2);   // bf16 after BN
    ushort* hpre   = (ushort*)carve((size_t)MP * 256 * 2);   // bf16 agg out
    ushort* xb     = (ushort*)carve((size_t)MP * 128 * 2);   // bf16 input
    ushort* w1t[3] = {(ushort*)carve(256 * 256 * 2), (ushort*)carve(256 * 256 * 2),
                      (ushort*)carve(256 * 256 * 2)};
    ushort* w2t[3] = {(ushort*)carve(256 * 256 * 2), (ushort*)carve(256 * 256 * 2),
                      (ushort*)carve(256 * 256 * 2)};
    ushort* lin1t  = (ushort*)carve((size_t)768 * 768 * 2);
    int*   row_st  = (int*)carve((size_t)(N + 1) * 4);
    int*   cursor  = (int*)carve((size_t)N * 4);
    int*   perm    = (int*)carve((size_t)E * 4);
    int*   csums   = (int*)carve(256 * 4);
    float* bnsums  = (float*)carve(512 * 4);
    float* part    = (float*)carve((size_t)6 * MP * 2 * 4);
    (void)ws_size;

    // ---- conversions ----
    cvt_f32_bf16<<<1024, 256, 0, stream>>>(x, xb, N * 64);
    WPrep wp;
    wp.src[0] = cW1[0]; wp.dst[0] = w1t[0]; wp.R[0] = 128; wp.C[0] = 256;
    wp.src[1] = cW1[1]; wp.dst[1] = w1t[1]; wp.R[1] = 256; wp.C[1] = 256;
    wp.src[2] = cW1[2]; wp.dst[2] = w1t[2]; wp.R[2] = 256; wp.C[2] = 256;
    wp.src[3] = cW2[0]; wp.dst[3] = w2t[0]; wp.R[3] = 256; wp.C[3] = 256;
    wp.src[4] = cW2[1]; wp.dst[4] = w2t[1]; wp.R[4] = 256; wp.C[4] = 256;
    wp.src[5] = cW2[2]; wp.dst[5] = w2t[2]; wp.R[5] = 256; wp.C[5] = 256;
    wp.src[6] = lin1_W; wp.dst[6] = lin1t;  wp.R[6] = 768; wp.C[6] = 768;
    prep_weights<<<dim3(576, 7), 256, 0, stream>>>(wp);

    // ---- CSR build (3-stage parallel scan) ----
    hipMemsetAsync(cursor, 0, (size_t)N * 4, stream);
    count_kernel<<<1024, 256, 0, stream>>>(ei, cursor, E);
    scan_chunk<<<nchunks, 256, 0, stream>>>(cursor, row_st, csums, N);
    scan_tops<<<1, 256, 0, stream>>>(csums, row_st, nchunks, N, E);
    scan_add<<<nchunks, 256, 0, stream>>>(row_st, cursor, csums, N);
    scatter_kernel<<<1024, 256, 0, stream>>>(ei, cursor, perm, E);

    const dim3 ggrid(2, MP / 128);       // conv GEMMs (784 WGs, %8==0)
    const int aggblocks = (N + 3) / 4;   // wave per node

    // ---- 3 GIN conv layers ----
    for (int L = 0; L < 3; ++L) {
        if (L == 0)
            agg2<128><<<aggblocks, 256, 0, stream>>>(xb, 128, row_st, perm, hpre, N);
        else
            agg2<256><<<aggblocks, 256, 0, stream>>>(Hcat + (size_t)(L - 1) * 256, 768,
                                                     row_st, perm, hpre, N);

        // GEMM1 + fused BN stats
        hipMemsetAsync(bnsums, 0, 512 * 4, stream);
        gemm_mfma<0><<<ggrid, 256, 0, stream>>>(
            hpre, w1t[L], cb1[L], hlin, 256, (L == 0) ? 128 : 256, bnsums, N);

        bn_apply<<<2048, 256, 0, stream>>>(hlin, bnsums, cg[L], cbe[L], hlin_b, N);

        // GEMM2 -> Hcat column block L (bf16, ldc=768)
        gemm_mfma<1><<<ggrid, 256, 0, stream>>>(
            hlin_b, w2t[L], cb2[L], (void*)(Hcat + (size_t)L * 256), 768, 256,
            nullptr, 0);
    }

    // ---- head: 256x128-tile fused gemm (lin1+relu+lin2 partials) ----
    gemm_head<<<dim3(6, MP / 256), 512, 0, stream>>>(
        Hcat, lin1t, lin1_b, lin2_W, part, 768, MP);

    finalize6<<<(N + 255) / 256, 256, 0, stream>>>(part, lin2_b, out, N, MP);
}

// Round 8
// 673.633 us; speedup vs baseline: 3.5129x; 1.0052x over previous
//
#include <hip/hip_runtime.h>
#include <hip/hip_bf16.h>

// ---------------------------------------------------------------------------
// GIN on MI355X: bf16 MFMA GEMMs with
//  - T2 LDS XOR-swizzle (bank-conflict-free, verified 2.17e7 -> 0 in R7)
//  - T4 counted-vmcnt double-buffer: raw s_barrier + s_waitcnt vmcnt(L) so the
//    next tile's global_load_lds stay in flight across the barrier (m218).
// Conv: 128x128/BK=32, fused BN-stats. Head: 256x128/BK=32, fused relu+lin2.
// ---------------------------------------------------------------------------

#define GIN_N_FEAT_IN 128
#define GIN_H 256
#define M_PAD_ROWS 50176   // 50000 padded to 256 (head tile height)

typedef short short8 __attribute__((ext_vector_type(8)));
typedef float f32x4 __attribute__((ext_vector_type(4)));

#define SCHED_FENCE() __builtin_amdgcn_sched_barrier(0)
#define RAW_BARRIER() __builtin_amdgcn_s_barrier()

__device__ inline ushort f32_to_bf16(float f) {
    union { float f; uint u; } x; x.f = f;
    uint r = x.u + 0x7fff + ((x.u >> 16) & 1);
    return (ushort)(r >> 16);
}
__device__ inline float bf16_to_f32(uint h) {
    union { uint u; float f; } x; x.u = h << 16;
    return x.f;
}
__device__ inline uint pack_bf16(float lo, float hi) {
    return (uint)f32_to_bf16(lo) | ((uint)f32_to_bf16(hi) << 16);
}

__device__ inline void gload_lds16(const ushort* g, ushort* l) {
    __builtin_amdgcn_global_load_lds(
        (const __attribute__((address_space(1))) void*)g,
        (__attribute__((address_space(3))) void*)l, 16, 0, 0);
}

// ---------------- conversions ----------------

__global__ void cvt_f32_bf16(const float* __restrict__ in, ushort* __restrict__ out, int npairs) {
    for (int i = blockIdx.x * blockDim.x + threadIdx.x; i < npairs; i += gridDim.x * blockDim.x) {
        float2 v = ((const float2*)in)[i];
        ((uint*)out)[i] = pack_bf16(v.x, v.y);
    }
}

// all weight transposes in one dispatch: dst[c][r] = bf16(src[r][c])
struct WPrep {
    const float* src[7];
    ushort* dst[7];
    int R[7];
    int C[7];
};

__global__ void prep_weights(WPrep p) {
    int which = blockIdx.y;
    int R = p.R[which], C = p.C[which];
    int total = R * C;
    const float* src = p.src[which];
    ushort* dst = p.dst[which];
    for (int idx = blockIdx.x * blockDim.x + threadIdx.x; idx < total;
         idx += gridDim.x * blockDim.x) {
        int r = idx / C, c = idx - r * C;
        dst[(size_t)c * R + r] = f32_to_bf16(src[idx]);
    }
}

// ---------------- CSR build ----------------

__global__ void count_kernel(const int* __restrict__ ei, int* __restrict__ deg, int E) {
    for (int e = blockIdx.x * blockDim.x + threadIdx.x; e < E; e += gridDim.x * blockDim.x) {
        atomicAdd(&deg[ei[E + e]], 1);   // dst = ei[1][e]
    }
}

__global__ void scan_chunk(const int* __restrict__ deg, int* __restrict__ row_start,
                           int* __restrict__ chunk_sums, int N) {
    __shared__ int sm[256];
    int tid = threadIdx.x;
    int idx = blockIdx.x * 256 + tid;
    int v = (idx < N) ? deg[idx] : 0;
    sm[tid] = v;
    __syncthreads();
    #pragma unroll
    for (int off = 1; off < 256; off <<= 1) {
        int t = (tid >= off) ? sm[tid - off] : 0;
        __syncthreads();
        sm[tid] += t;
        __syncthreads();
    }
    if (idx < N) row_start[idx] = sm[tid] - v;
    if (tid == 255) chunk_sums[blockIdx.x] = sm[255];
}

__global__ void scan_tops(int* __restrict__ chunk_sums, int* __restrict__ row_start,
                          int nchunks, int N, int E) {
    __shared__ int sm[256];
    int tid = threadIdx.x;
    int v = (tid < nchunks) ? chunk_sums[tid] : 0;
    sm[tid] = v;
    __syncthreads();
    #pragma unroll
    for (int off = 1; off < 256; off <<= 1) {
        int t = (tid >= off) ? sm[tid - off] : 0;
        __syncthreads();
        sm[tid] += t;
        __syncthreads();
    }
    if (tid < nchunks) chunk_sums[tid] = sm[tid] - v;
    if (tid == 0) row_start[N] = E;
}

__global__ void scan_add(int* __restrict__ row_start, int* __restrict__ cursor,
                         const int* __restrict__ chunk_sums, int N) {
    int idx = blockIdx.x * 256 + threadIdx.x;
    if (idx < N) {
        int v = row_start[idx] + chunk_sums[blockIdx.x];
        row_start[idx] = v;
        cursor[idx] = v;
    }
}

__global__ void scatter_kernel(const int* __restrict__ ei, int* __restrict__ cursor,
                               int* __restrict__ perm, int E) {
    for (int e = blockIdx.x * blockDim.x + threadIdx.x; e < E; e += gridDim.x * blockDim.x) {
        int d = ei[E + e];
        int pos = atomicAdd(&cursor[d], 1);
        perm[pos] = ei[e];
    }
}

// ---------------- aggregation: wave-per-node, unroll-4 ILP ----------------

template <int W>
__global__ void agg2(const ushort* __restrict__ xsrc, int stride,
                     const int* __restrict__ row_start, const int* __restrict__ perm,
                     ushort* __restrict__ out, int N) {
    constexpr int PL = W / 64;                 // bf16 per lane: 2 or 4
    int node = blockIdx.x * 4 + (threadIdx.x >> 6);
    if (node >= N) return;
    const int lane = threadIdx.x & 63;
    const size_t loff = (size_t)lane * PL;

    float af[PL];
    {
        const ushort* p = xsrc + (size_t)node * stride + loff;
        if constexpr (W == 256) {
            uint2 v = *(const uint2*)p;
            af[0] = bf16_to_f32(v.x & 0xffffu); af[1] = bf16_to_f32(v.x >> 16);
            af[2] = bf16_to_f32(v.y & 0xffffu); af[3] = bf16_to_f32(v.y >> 16);
        } else {
            uint v = *(const uint*)p;
            af[0] = bf16_to_f32(v & 0xffffu); af[1] = bf16_to_f32(v >> 16);
        }
    }
    const int s = row_start[node], e = row_start[node + 1];
    int j = s;
    for (; j + 4 <= e; j += 4) {
        int n0 = perm[j], n1 = perm[j + 1], n2 = perm[j + 2], n3 = perm[j + 3];
        if constexpr (W == 256) {
            uint2 w0 = *(const uint2*)(xsrc + (size_t)n0 * stride + loff);
            uint2 w1 = *(const uint2*)(xsrc + (size_t)n1 * stride + loff);
            uint2 w2 = *(const uint2*)(xsrc + (size_t)n2 * stride + loff);
            uint2 w3 = *(const uint2*)(xsrc + (size_t)n3 * stride + loff);
            af[0] += bf16_to_f32(w0.x & 0xffffu) + bf16_to_f32(w1.x & 0xffffu)
                   + bf16_to_f32(w2.x & 0xffffu) + bf16_to_f32(w3.x & 0xffffu);
            af[1] += bf16_to_f32(w0.x >> 16) + bf16_to_f32(w1.x >> 16)
                   + bf16_to_f32(w2.x >> 16) + bf16_to_f32(w3.x >> 16);
            af[2] += bf16_to_f32(w0.y & 0xffffu) + bf16_to_f32(w1.y & 0xffffu)
                   + bf16_to_f32(w2.y & 0xffffu) + bf16_to_f32(w3.y & 0xffffu);
            af[3] += bf16_to_f32(w0.y >> 16) + bf16_to_f32(w1.y >> 16)
                   + bf16_to_f32(w2.y >> 16) + bf16_to_f32(w3.y >> 16);
        } else {
            uint w0 = *(const uint*)(xsrc + (size_t)n0 * stride + loff);
            uint w1 = *(const uint*)(xsrc + (size_t)n1 * stride + loff);
            uint w2 = *(const uint*)(xsrc + (size_t)n2 * stride + loff);
            uint w3 = *(const uint*)(xsrc + (size_t)n3 * stride + loff);
            af[0] += bf16_to_f32(w0 & 0xffffu) + bf16_to_f32(w1 & 0xffffu)
                   + bf16_to_f32(w2 & 0xffffu) + bf16_to_f32(w3 & 0xffffu);
            af[1] += bf16_to_f32(w0 >> 16) + bf16_to_f32(w1 >> 16)
                   + bf16_to_f32(w2 >> 16) + bf16_to_f32(w3 >> 16);
        }
    }
    for (; j < e; ++j) {
        int sn = perm[j];
        const ushort* p = xsrc + (size_t)sn * stride + loff;
        if constexpr (W == 256) {
            uint2 w = *(const uint2*)p;
            af[0] += bf16_to_f32(w.x & 0xffffu); af[1] += bf16_to_f32(w.x >> 16);
            af[2] += bf16_to_f32(w.y & 0xffffu); af[3] += bf16_to_f32(w.y >> 16);
        } else {
            uint w = *(const uint*)p;
            af[0] += bf16_to_f32(w & 0xffffu); af[1] += bf16_to_f32(w >> 16);
        }
    }
    ushort* po = out + (size_t)node * W + loff;
    if constexpr (W == 256) {
        uint2 o; o.x = pack_bf16(af[0], af[1]); o.y = pack_bf16(af[2], af[3]);
        *(uint2*)po = o;
    } else {
        *(uint*)po = pack_bf16(af[0], af[1]);
    }
}

// ---------------- conv bf16 MFMA GEMM: 128x128, BK=32, T4 dbuf + T2 swizzle --
// MODE 0: f32 store + fused BN stats; MODE 1: bf16 store + relu.

template <int MODE>
__global__ __launch_bounds__(256) void gemm_mfma(
    const ushort* __restrict__ A, const ushort* __restrict__ Bt,
    const float* __restrict__ bias, void* __restrict__ Cout,
    int ldc, int K, float* __restrict__ extra, int Nvalid) {
    __shared__ ushort As[2][128 * 32];
    __shared__ ushort Bs[2][128 * 32];
    const int tid = threadIdx.x;

    // XCD-bijective chunked swizzle (m204)
    const int gx = gridDim.x;
    const int nwg = gx * gridDim.y;
    const int flat = blockIdx.y * gx + blockIdx.x;
    const int q = nwg >> 3, r = nwg & 7;
    const int xcd = flat & 7, loc = flat >> 3;
    const int wg = (xcd < r ? xcd * (q + 1) : r * (q + 1) + (xcd - r) * q) + loc;
    const int bm = (wg / gx) * 128;
    const int bn = (wg % gx) * 128;

    const int lane = tid & 63;
    const int wid = tid >> 6;
    const int wr = wid >> 1, wc = wid & 1;

    f32x4 acc[4][4] = {};

    // staging: thread t -> row t>>2 (per 64-row half), stored chunk t&3.
    // global column chunk = (t&3) ^ ((t>>3)&3)  [inverse of stored swizzle]
    const int arow = tid >> 2;
    const int gcol = ((tid & 3) ^ ((tid >> 3) & 3)) * 8;
    const ushort* Ag0 = A + (size_t)(bm + arow) * K + gcol;
    const ushort* Ag1 = A + (size_t)(bm + 64 + arow) * K + gcol;
    const ushort* Bg0 = Bt + (size_t)(bn + arow) * K + gcol;
    const ushort* Bg1 = Bt + (size_t)(bn + 64 + arow) * K + gcol;
    const int wofs = (tid & ~63) * 8;   // wave-uniform LDS base, HW adds lane*16B

    const int fr = lane & 15;
    // read: logical chunk = lane>>4; stored = chunk ^ ((row>>1)&3), row%16==fr
    const int rchunk = ((lane >> 4) ^ ((fr >> 1) & 3)) * 8;

    const int NT = K >> 5;

    // prologue: stage tile 0 into buf 0 (4 loads in flight)
    {
        ushort* a = As[0]; ushort* b = Bs[0];
        gload_lds16(Ag0, a + wofs);
        gload_lds16(Ag1, a + 2048 + wofs);
        gload_lds16(Bg0, b + wofs);
        gload_lds16(Bg1, b + 2048 + wofs);
    }

    for (int it = 0; it < NT; ++it) {
        if (it + 1 < NT) {                      // prefetch next tile (4 more loads)
            const int k0 = (it + 1) << 5;
            ushort* a = As[(it + 1) & 1]; ushort* b = Bs[(it + 1) & 1];
            gload_lds16(Ag0 + k0, a + wofs);
            gload_lds16(Ag1 + k0, a + 2048 + wofs);
            gload_lds16(Bg0 + k0, b + wofs);
            gload_lds16(Bg1 + k0, b + 2048 + wofs);
            asm volatile("s_waitcnt vmcnt(4)" ::: "memory");   // tile it done, it+1 in flight
        } else {
            asm volatile("s_waitcnt vmcnt(0)" ::: "memory");
        }
        SCHED_FENCE();
        RAW_BARRIER();                           // all waves: tile it LDS-ready

        const ushort* as = As[it & 1];
        const ushort* bs = Bs[it & 1];
        short8 af[4], bf[4];
        #pragma unroll
        for (int m = 0; m < 4; ++m)
            af[m] = *(const short8*)&as[(wr * 64 + m * 16 + fr) * 32 + rchunk];
        #pragma unroll
        for (int n = 0; n < 4; ++n)
            bf[n] = *(const short8*)&bs[(wc * 64 + n * 16 + fr) * 32 + rchunk];
        #pragma unroll
        for (int m = 0; m < 4; ++m)
            #pragma unroll
            for (int n = 0; n < 4; ++n)
                acc[m][n] = __builtin_amdgcn_mfma_f32_16x16x32_bf16(af[m], bf[n], acc[m][n], 0, 0, 0);

        asm volatile("s_waitcnt lgkmcnt(0)" ::: "memory");     // reads of buf done
        SCHED_FENCE();
        RAW_BARRIER();                           // safe to overwrite buf next iter
    }

    // epilogue: C/D layout col=lane&15, row=(lane>>4)*4+reg
    float s1[4], s2[4];
    if constexpr (MODE == 0) {
        #pragma unroll
        for (int n = 0; n < 4; ++n) { s1[n] = 0.f; s2[n] = 0.f; }
    }
    #pragma unroll
    for (int n = 0; n < 4; ++n) {
        const int col = bn + wc * 64 + n * 16 + fr;
        const float bv = bias[col];
        #pragma unroll
        for (int m = 0; m < 4; ++m) {
            const int row0 = bm + wr * 64 + m * 16 + (lane >> 4) * 4;
            #pragma unroll
            for (int rr = 0; rr < 4; ++rr) {
                float v = acc[m][n][rr] + bv;
                if constexpr (MODE == 1) {
                    v = fmaxf(v, 0.f);
                    ((ushort*)Cout)[(size_t)(row0 + rr) * ldc + col] = f32_to_bf16(v);
                } else {
                    ((float*)Cout)[(size_t)(row0 + rr) * ldc + col] = v;
                    if (row0 + rr < Nvalid) { s1[n] += v; s2[n] += v * v; }
                }
            }
        }
    }
    if constexpr (MODE == 0) {
        #pragma unroll
        for (int n = 0; n < 4; ++n) {
            float a = s1[n], b = s2[n];
            a += __shfl_xor(a, 16); b += __shfl_xor(b, 16);
            a += __shfl_xor(a, 32); b += __shfl_xor(b, 32);
            if ((lane >> 4) == 0) {
                int col = bn + wc * 64 + n * 16 + fr;
                atomicAdd(&extra[col], a);
                atomicAdd(&extra[256 + col], b);
            }
        }
    }
}

// ---------------- head GEMM: 256x128, BK=32, 8 waves, T4 dbuf + T2 swizzle ---
// T-tile = relu(Hcat[256x768] @ lin1t^T[128x768] + b); fused lin2 dot ->
// part[coltile][row][0..1].  Atomic-free global (LDS combine).

__global__ __launch_bounds__(512) void gemm_head(
    const ushort* __restrict__ A,    // Hcat [MP x 768]
    const ushort* __restrict__ Bt,   // lin1t [768 x 768]
    const float* __restrict__ bias,  // lin1_b [768]
    const float* __restrict__ w2,    // lin2_W [768 x 2]
    float* __restrict__ part,        // [6][MP][2]
    int K, int MP) {
    __shared__ ushort As[2][256 * 32];  // 32 KB
    __shared__ ushort Bs[2][128 * 32];  // 16 KB
    __shared__ float sm_part[256][2];   // 2 KB   -> 50 KB total, 3 blocks/CU
    const int tid = threadIdx.x;

    // XCD-bijective swizzle (nwg = 6*196 = 1176, %8==0)
    const int gx = gridDim.x;
    const int nwg = gx * gridDim.y;
    const int flat = blockIdx.y * gx + blockIdx.x;
    const int q = nwg >> 3, r = nwg & 7;
    const int xcd = flat & 7, loc = flat >> 3;
    const int wg = (xcd < r ? xcd * (q + 1) : r * (q + 1) + (xcd - r) * q) + loc;
    const int bm = (wg / gx) * 256;
    const int bn = (wg % gx) * 128;
    const int coltile = wg % gx;

    const int lane = tid & 63;
    const int wid = tid >> 6;        // 0..7
    const int wr = wid >> 1;         // 0..3 (64-row band of 256)
    const int wc = wid & 1;          // 0..1 (64-col half of 128)

    sm_part[tid >> 1][tid & 1] = 0.f;

    f32x4 acc[4][4] = {};

    // staging: thread t -> row t>>2 (0..127 per section), stored chunk t&3;
    // global column chunk = (t&3) ^ ((t>>3)&3)
    const int arow = tid >> 2;
    const int gcol = ((tid & 3) ^ ((tid >> 3) & 3)) * 8;
    const ushort* Ag0 = A + (size_t)(bm + arow) * K + gcol;         // rows 0..127
    const ushort* Ag1 = A + (size_t)(bm + 128 + arow) * K + gcol;   // rows 128..255
    const ushort* Bg0 = Bt + (size_t)(bn + arow) * K + gcol;        // 128 rows
    const int wofs = (tid & ~63) * 8;

    const int fr = lane & 15;
    const int rchunk = ((lane >> 4) ^ ((fr >> 1) & 3)) * 8;

    const int NT = K >> 5;   // 24

    {   // prologue: 3 loads in flight
        ushort* a = As[0]; ushort* b = Bs[0];
        gload_lds16(Ag0, a + wofs);
        gload_lds16(Ag1, a + 4096 + wofs);
        gload_lds16(Bg0, b + wofs);
    }

    for (int it = 0; it < NT; ++it) {
        if (it + 1 < NT) {
            const int k0 = (it + 1) << 5;
            ushort* a = As[(it + 1) & 1]; ushort* b = Bs[(it + 1) & 1];
            gload_lds16(Ag0 + k0, a + wofs);
            gload_lds16(Ag1 + k0, a + 4096 + wofs);
            gload_lds16(Bg0 + k0, b + wofs);
            asm volatile("s_waitcnt vmcnt(3)" ::: "memory");   // tile it done
        } else {
            asm volatile("s_waitcnt vmcnt(0)" ::: "memory");
        }
        SCHED_FENCE();
        RAW_BARRIER();

        const ushort* as = As[it & 1];
        const ushort* bs = Bs[it & 1];
        short8 af[4], bf[4];
        #pragma unroll
        for (int m = 0; m < 4; ++m)
            af[m] = *(const short8*)&as[(wr * 64 + m * 16 + fr) * 32 + rchunk];
        #pragma unroll
        for (int n = 0; n < 4; ++n)
            bf[n] = *(const short8*)&bs[(wc * 64 + n * 16 + fr) * 32 + rchunk];
        #pragma unroll
        for (int m = 0; m < 4; ++m)
            #pragma unroll
            for (int n = 0; n < 4; ++n)
                acc[m][n] = __builtin_amdgcn_mfma_f32_16x16x32_bf16(af[m], bf[n], acc[m][n], 0, 0, 0);

        asm volatile("s_waitcnt lgkmcnt(0)" ::: "memory");
        SCHED_FENCE();
        RAW_BARRIER();
    }

    // epilogue: relu(v+bias) dot w2 -> reduce over fr -> LDS combine
    #pragma unroll
    for (int m = 0; m < 4; ++m) {
        #pragma unroll
        for (int rr = 0; rr < 4; ++rr) {
            float o0 = 0.f, o1 = 0.f;
            #pragma unroll
            for (int n = 0; n < 4; ++n) {
                int col = bn + wc * 64 + n * 16 + fr;
                float v = fmaxf(acc[m][n][rr] + bias[col], 0.f);
                o0 = fmaf(v, w2[col * 2 + 0], o0);
                o1 = fmaf(v, w2[col * 2 + 1], o1);
            }
            o0 += __shfl_xor(o0, 1); o1 += __shfl_xor(o1, 1);
            o0 += __shfl_xor(o0, 2); o1 += __shfl_xor(o1, 2);
            o0 += __shfl_xor(o0, 4); o1 += __shfl_xor(o1, 4);
            o0 += __shfl_xor(o0, 8); o1 += __shfl_xor(o1, 8);
            if (fr == 0) {
                int lrow = wr * 64 + m * 16 + (lane >> 4) * 4 + rr;
                atomicAdd(&sm_part[lrow][0], o0);
                atomicAdd(&sm_part[lrow][1], o1);
            }
        }
    }
    __syncthreads();
    {
        int lrow = tid >> 1, comp = tid & 1;
        part[((size_t)coltile * MP + bm + lrow) * 2 + comp] = sm_part[lrow][comp];
    }
}

// ---------------- BN apply (normalize + relu, write bf16) ----------------

__global__ void bn_apply(const float* __restrict__ h, const float* __restrict__ sums,
                         const float* __restrict__ g, const float* __restrict__ be,
                         ushort* __restrict__ outb, int Nrows) {
    int total = Nrows * 128;
    float inv = 1.0f / (float)Nrows;
    for (int idx = blockIdx.x * blockDim.x + threadIdx.x; idx < total;
         idx += gridDim.x * blockDim.x) {
        int row = idx >> 7;
        int cp = (idx & 127) * 2;
        float2 v = *(const float2*)(h + (size_t)row * 256 + cp);
        float mu0 = sums[cp] * inv,     mu1 = sums[cp + 1] * inv;
        float va0 = sums[256 + cp] * inv - mu0 * mu0;
        float va1 = sums[257 + cp] * inv - mu1 * mu1;
        float o0 = fmaxf((v.x - mu0) * rsqrtf(va0 + 1e-5f) * g[cp]     + be[cp],     0.f);
        float o1 = fmaxf((v.y - mu1) * rsqrtf(va1 + 1e-5f) * g[cp + 1] + be[cp + 1], 0.f);
        *(uint*)(outb + (size_t)row * 256 + cp) = pack_bf16(o0, o1);
    }
}

// ---------------- finalize: sum 6 partials + bias + softmax ----------------

__global__ void finalize6(const float* __restrict__ part, const float* __restrict__ b2,
                          float* __restrict__ out, int Nrows, int MP) {
    int i = blockIdx.x * blockDim.x + threadIdx.x;
    if (i >= Nrows) return;
    float h0 = b2[0], h1 = b2[1];
    #pragma unroll
    for (int c = 0; c < 6; ++c) {
        h0 += part[((size_t)c * MP + i) * 2 + 0];
        h1 += part[((size_t)c * MP + i) * 2 + 1];
    }
    out[2 * i] = h0;
    out[2 * i + 1] = h1;
    float m = fmaxf(h0, h1);
    float e0 = expf(h0 - m), e1 = expf(h1 - m);
    float s = e0 + e1;
    out[(size_t)2 * Nrows + 2 * i] = e0 / s;
    out[(size_t)2 * Nrows + 2 * i + 1] = e1 / s;
}

// ---------------------------------------------------------------------------

extern "C" void kernel_launch(void* const* d_in, const int* in_sizes, int n_in,
                              void* d_out, int out_size, void* d_ws, size_t ws_size,
                              hipStream_t stream) {
    const int N = in_sizes[0] / GIN_N_FEAT_IN;     // 50000
    const int E = in_sizes[1] / 2;                 // 800000
    const int MP = M_PAD_ROWS;
    const int nchunks = (N + 255) / 256;           // 196

    const float* x  = (const float*)d_in[0];
    const int*   ei = (const int*)d_in[1];
    const float* cW1[3] = {(const float*)d_in[2],  (const float*)d_in[8],  (const float*)d_in[14]};
    const float* cb1[3] = {(const float*)d_in[3],  (const float*)d_in[9],  (const float*)d_in[15]};
    const float* cg [3] = {(const float*)d_in[4],  (const float*)d_in[10], (const float*)d_in[16]};
    const float* cbe[3] = {(const float*)d_in[5],  (const float*)d_in[11], (const float*)d_in[17]};
    const float* cW2[3] = {(const float*)d_in[6],  (const float*)d_in[12], (const float*)d_in[18]};
    const float* cb2[3] = {(const float*)d_in[7],  (const float*)d_in[13], (const float*)d_in[19]};
    const float* lin1_W = (const float*)d_in[20];  // [768,768]
    const float* lin1_b = (const float*)d_in[21];
    const float* lin2_W = (const float*)d_in[22];  // [768,2]
    const float* lin2_b = (const float*)d_in[23];
    float* out = (float*)d_out;

    // ---- workspace carve-up (row buffers padded to MP rows) ----
    char* ws = (char*)d_ws;
    size_t off = 0;
    auto carve = [&](size_t bytes) {
        void* p = ws + off;
        off += (bytes + 255) & ~(size_t)255;
        return p;
    };
    ushort* Hcat   = (ushort*)carve((size_t)MP * 768 * 2);   // bf16 h1|h2|h3
    float*  hlin   = (float*) carve((size_t)MP * 256 * 4);   // f32 gemm1 out
    ushort* hlin_b = (ushort*)carve((size_t)MP * 256 * 2);   // bf16 after BN
    ushort* hpre   = (ushort*)carve((size_t)MP * 256 * 2);   // bf16 agg out
    ushort* xb     = (ushort*)carve((size_t)MP * 128 * 2);   // bf16 input
    ushort* w1t[3] = {(ushort*)carve(256 * 256 * 2), (ushort*)carve(256 * 256 * 2),
                      (ushort*)carve(256 * 256 * 2)};
    ushort* w2t[3] = {(ushort*)carve(256 * 256 * 2), (ushort*)carve(256 * 256 * 2),
                      (ushort*)carve(256 * 256 * 2)};
    ushort* lin1t  = (ushort*)carve((size_t)768 * 768 * 2);
    int*   row_st  = (int*)carve((size_t)(N + 1) * 4);
    int*   cursor  = (int*)carve((size_t)N * 4);
    int*   perm    = (int*)carve((size_t)E * 4);
    int*   csums   = (int*)carve(256 * 4);
    float* bnsums  = (float*)carve(512 * 4);
    float* part    = (float*)carve((size_t)6 * MP * 2 * 4);
    (void)ws_size;

    // ---- conversions ----
    cvt_f32_bf16<<<1024, 256, 0, stream>>>(x, xb, N * 64);
    WPrep wp;
    wp.src[0] = cW1[0]; wp.dst[0] = w1t[0]; wp.R[0] = 128; wp.C[0] = 256;
    wp.src[1] = cW1[1]; wp.dst[1] = w1t[1]; wp.R[1] = 256; wp.C[1] = 256;
    wp.src[2] = cW1[2]; wp.dst[2] = w1t[2]; wp.R[2] = 256; wp.C[2] = 256;
    wp.src[3] = cW2[0]; wp.dst[3] = w2t[0]; wp.R[3] = 256; wp.C[3] = 256;
    wp.src[4] = cW2[1]; wp.dst[4] = w2t[1]; wp.R[4] = 256; wp.C[4] = 256;
    wp.src[5] = cW2[2]; wp.dst[5] = w2t[2]; wp.R[5] = 256; wp.C[5] = 256;
    wp.src[6] = lin1_W; wp.dst[6] = lin1t;  wp.R[6] = 768; wp.C[6] = 768;
    prep_weights<<<dim3(576, 7), 256, 0, stream>>>(wp);

    // ---- CSR build (3-stage parallel scan) ----
    hipMemsetAsync(cursor, 0, (size_t)N * 4, stream);
    count_kernel<<<1024, 256, 0, stream>>>(ei, cursor, E);
    scan_chunk<<<nchunks, 256, 0, stream>>>(cursor, row_st, csums, N);
    scan_tops<<<1, 256, 0, stream>>>(csums, row_st, nchunks, N, E);
    scan_add<<<nchunks, 256, 0, stream>>>(row_st, cursor, csums, N);
    scatter_kernel<<<1024, 256, 0, stream>>>(ei, cursor, perm, E);

    const dim3 ggrid(2, MP / 128);       // conv GEMMs (784 WGs, %8==0)
    const int aggblocks = (N + 3) / 4;   // wave per node

    // ---- 3 GIN conv layers ----
    for (int L = 0; L < 3; ++L) {
        if (L == 0)
            agg2<128><<<aggblocks, 256, 0, stream>>>(xb, 128, row_st, perm, hpre, N);
        else
            agg2<256><<<aggblocks, 256, 0, stream>>>(Hcat + (size_t)(L - 1) * 256, 768,
                                                     row_st, perm, hpre, N);

        // GEMM1 + fused BN stats
        hipMemsetAsync(bnsums, 0, 512 * 4, stream);
        gemm_mfma<0><<<ggrid, 256, 0, stream>>>(
            hpre, w1t[L], cb1[L], hlin, 256, (L == 0) ? 128 : 256, bnsums, N);

        bn_apply<<<2048, 256, 0, stream>>>(hlin, bnsums, cg[L], cbe[L], hlin_b, N);

        // GEMM2 -> Hcat column block L (bf16, ldc=768)
        gemm_mfma<1><<<ggrid, 256, 0, stream>>>(
            hlin_b, w2t[L], cb2[L], (void*)(Hcat + (size_t)L * 256), 768, 256,
            nullptr, 0);
    }

    // ---- head: 256x128-tile fused gemm (lin1+relu+lin2 partials) ----
    gemm_head<<<dim3(6, MP / 256), 512, 0, stream>>>(
        Hcat, lin1t, lin1_b, lin2_W, part, 768, MP);

    finalize6<<<(N + 255) / 256, 256, 0, stream>>>(part, lin2_b, out, N, MP);
}

// Round 9
// 671.484 us; speedup vs baseline: 3.5241x; 1.0032x over previous
//
#include <hip/hip_runtime.h>
#include <hip/hip_bf16.h>

// ---------------------------------------------------------------------------
// GIN on MI355X: bf16 MFMA GEMMs with
//  - T2 LDS XOR-swizzle (bank-conflict-free, verified 2.17e7 -> 0 in R7)
//  - ring-3 LDS, depth-2 prefetch, counted vmcnt (never drains in steady state)
//  - T5 s_setprio around the MFMA cluster
// Conv: 128x128/BK=32, fused BN-stats. Head: 256x128/BK=32, fused relu+lin2.
// ---------------------------------------------------------------------------

#define GIN_N_FEAT_IN 128
#define GIN_H 256
#define M_PAD_ROWS 50176   // 50000 padded to 256 (head tile height)

typedef short short8 __attribute__((ext_vector_type(8)));
typedef float f32x4 __attribute__((ext_vector_type(4)));

#define SCHED_FENCE() __builtin_amdgcn_sched_barrier(0)
#define RAW_BARRIER() __builtin_amdgcn_s_barrier()

__device__ inline ushort f32_to_bf16(float f) {
    union { float f; uint u; } x; x.f = f;
    uint r = x.u + 0x7fff + ((x.u >> 16) & 1);
    return (ushort)(r >> 16);
}
__device__ inline float bf16_to_f32(uint h) {
    union { uint u; float f; } x; x.u = h << 16;
    return x.f;
}
__device__ inline uint pack_bf16(float lo, float hi) {
    return (uint)f32_to_bf16(lo) | ((uint)f32_to_bf16(hi) << 16);
}

__device__ inline void gload_lds16(const ushort* g, ushort* l) {
    __builtin_amdgcn_global_load_lds(
        (const __attribute__((address_space(1))) void*)g,
        (__attribute__((address_space(3))) void*)l, 16, 0, 0);
}

// ---------------- conversions ----------------

__global__ void cvt_f32_bf16(const float* __restrict__ in, ushort* __restrict__ out, int npairs) {
    for (int i = blockIdx.x * blockDim.x + threadIdx.x; i < npairs; i += gridDim.x * blockDim.x) {
        float2 v = ((const float2*)in)[i];
        ((uint*)out)[i] = pack_bf16(v.x, v.y);
    }
}

// all weight transposes in one dispatch: dst[c][r] = bf16(src[r][c])
struct WPrep {
    const float* src[7];
    ushort* dst[7];
    int R[7];
    int C[7];
};

__global__ void prep_weights(WPrep p) {
    int which = blockIdx.y;
    int R = p.R[which], C = p.C[which];
    int total = R * C;
    const float* src = p.src[which];
    ushort* dst = p.dst[which];
    for (int idx = blockIdx.x * blockDim.x + threadIdx.x; idx < total;
         idx += gridDim.x * blockDim.x) {
        int r = idx / C, c = idx - r * C;
        dst[(size_t)c * R + r] = f32_to_bf16(src[idx]);
    }
}

// ---------------- CSR build ----------------

__global__ void count_kernel(const int* __restrict__ ei, int* __restrict__ deg, int E) {
    for (int e = blockIdx.x * blockDim.x + threadIdx.x; e < E; e += gridDim.x * blockDim.x) {
        atomicAdd(&deg[ei[E + e]], 1);   // dst = ei[1][e]
    }
}

__global__ void scan_chunk(const int* __restrict__ deg, int* __restrict__ row_start,
                           int* __restrict__ chunk_sums, int N) {
    __shared__ int sm[256];
    int tid = threadIdx.x;
    int idx = blockIdx.x * 256 + tid;
    int v = (idx < N) ? deg[idx] : 0;
    sm[tid] = v;
    __syncthreads();
    #pragma unroll
    for (int off = 1; off < 256; off <<= 1) {
        int t = (tid >= off) ? sm[tid - off] : 0;
        __syncthreads();
        sm[tid] += t;
        __syncthreads();
    }
    if (idx < N) row_start[idx] = sm[tid] - v;
    if (tid == 255) chunk_sums[blockIdx.x] = sm[255];
}

__global__ void scan_tops(int* __restrict__ chunk_sums, int* __restrict__ row_start,
                          int nchunks, int N, int E) {
    __shared__ int sm[256];
    int tid = threadIdx.x;
    int v = (tid < nchunks) ? chunk_sums[tid] : 0;
    sm[tid] = v;
    __syncthreads();
    #pragma unroll
    for (int off = 1; off < 256; off <<= 1) {
        int t = (tid >= off) ? sm[tid - off] : 0;
        __syncthreads();
        sm[tid] += t;
        __syncthreads();
    }
    if (tid < nchunks) chunk_sums[tid] = sm[tid] - v;
    if (tid == 0) row_start[N] = E;
}

__global__ void scan_add(int* __restrict__ row_start, int* __restrict__ cursor,
                         const int* __restrict__ chunk_sums, int N) {
    int idx = blockIdx.x * 256 + threadIdx.x;
    if (idx < N) {
        int v = row_start[idx] + chunk_sums[blockIdx.x];
        row_start[idx] = v;
        cursor[idx] = v;
    }
}

__global__ void scatter_kernel(const int* __restrict__ ei, int* __restrict__ cursor,
                               int* __restrict__ perm, int E) {
    for (int e = blockIdx.x * blockDim.x + threadIdx.x; e < E; e += gridDim.x * blockDim.x) {
        int d = ei[E + e];
        int pos = atomicAdd(&cursor[d], 1);
        perm[pos] = ei[e];
    }
}

// ---------------- aggregation: wave-per-node, unroll-4 ILP ----------------

template <int W>
__global__ void agg2(const ushort* __restrict__ xsrc, int stride,
                     const int* __restrict__ row_start, const int* __restrict__ perm,
                     ushort* __restrict__ out, int N) {
    constexpr int PL = W / 64;                 // bf16 per lane: 2 or 4
    int node = blockIdx.x * 4 + (threadIdx.x >> 6);
    if (node >= N) return;
    const int lane = threadIdx.x & 63;
    const size_t loff = (size_t)lane * PL;

    float af[PL];
    {
        const ushort* p = xsrc + (size_t)node * stride + loff;
        if constexpr (W == 256) {
            uint2 v = *(const uint2*)p;
            af[0] = bf16_to_f32(v.x & 0xffffu); af[1] = bf16_to_f32(v.x >> 16);
            af[2] = bf16_to_f32(v.y & 0xffffu); af[3] = bf16_to_f32(v.y >> 16);
        } else {
            uint v = *(const uint*)p;
            af[0] = bf16_to_f32(v & 0xffffu); af[1] = bf16_to_f32(v >> 16);
        }
    }
    const int s = row_start[node], e = row_start[node + 1];
    int j = s;
    for (; j + 4 <= e; j += 4) {
        int n0 = perm[j], n1 = perm[j + 1], n2 = perm[j + 2], n3 = perm[j + 3];
        if constexpr (W == 256) {
            uint2 w0 = *(const uint2*)(xsrc + (size_t)n0 * stride + loff);
            uint2 w1 = *(const uint2*)(xsrc + (size_t)n1 * stride + loff);
            uint2 w2 = *(const uint2*)(xsrc + (size_t)n2 * stride + loff);
            uint2 w3 = *(const uint2*)(xsrc + (size_t)n3 * stride + loff);
            af[0] += bf16_to_f32(w0.x & 0xffffu) + bf16_to_f32(w1.x & 0xffffu)
                   + bf16_to_f32(w2.x & 0xffffu) + bf16_to_f32(w3.x & 0xffffu);
            af[1] += bf16_to_f32(w0.x >> 16) + bf16_to_f32(w1.x >> 16)
                   + bf16_to_f32(w2.x >> 16) + bf16_to_f32(w3.x >> 16);
            af[2] += bf16_to_f32(w0.y & 0xffffu) + bf16_to_f32(w1.y & 0xffffu)
                   + bf16_to_f32(w2.y & 0xffffu) + bf16_to_f32(w3.y & 0xffffu);
            af[3] += bf16_to_f32(w0.y >> 16) + bf16_to_f32(w1.y >> 16)
                   + bf16_to_f32(w2.y >> 16) + bf16_to_f32(w3.y >> 16);
        } else {
            uint w0 = *(const uint*)(xsrc + (size_t)n0 * stride + loff);
            uint w1 = *(const uint*)(xsrc + (size_t)n1 * stride + loff);
            uint w2 = *(const uint*)(xsrc + (size_t)n2 * stride + loff);
            uint w3 = *(const uint*)(xsrc + (size_t)n3 * stride + loff);
            af[0] += bf16_to_f32(w0 & 0xffffu) + bf16_to_f32(w1 & 0xffffu)
                   + bf16_to_f32(w2 & 0xffffu) + bf16_to_f32(w3 & 0xffffu);
            af[1] += bf16_to_f32(w0 >> 16) + bf16_to_f32(w1 >> 16)
                   + bf16_to_f32(w2 >> 16) + bf16_to_f32(w3 >> 16);
        }
    }
    for (; j < e; ++j) {
        int sn = perm[j];
        const ushort* p = xsrc + (size_t)sn * stride + loff;
        if constexpr (W == 256) {
            uint2 w = *(const uint2*)p;
            af[0] += bf16_to_f32(w.x & 0xffffu); af[1] += bf16_to_f32(w.x >> 16);
            af[2] += bf16_to_f32(w.y & 0xffffu); af[3] += bf16_to_f32(w.y >> 16);
        } else {
            uint w = *(const uint*)p;
            af[0] += bf16_to_f32(w & 0xffffu); af[1] += bf16_to_f32(w >> 16);
        }
    }
    ushort* po = out + (size_t)node * W + loff;
    if constexpr (W == 256) {
        uint2 o; o.x = pack_bf16(af[0], af[1]); o.y = pack_bf16(af[2], af[3]);
        *(uint2*)po = o;
    } else {
        *(uint*)po = pack_bf16(af[0], af[1]);
    }
}

// ---------------- conv bf16 MFMA GEMM: 128x128, BK=32, ring-3 depth-2 --------
// MODE 0: f32 store + fused BN stats; MODE 1: bf16 store + relu.

template <int MODE>
__global__ __launch_bounds__(256) void gemm_mfma(
    const ushort* __restrict__ A, const ushort* __restrict__ Bt,
    const float* __restrict__ bias, void* __restrict__ Cout,
    int ldc, int K, float* __restrict__ extra, int Nvalid) {
    __shared__ ushort As[3][128 * 32];   // 24 KB
    __shared__ ushort Bs[3][128 * 32];   // 24 KB  -> 48 KB, 3 blocks/CU
    const int tid = threadIdx.x;

    // XCD-bijective chunked swizzle (m204)
    const int gx = gridDim.x;
    const int nwg = gx * gridDim.y;
    const int flat = blockIdx.y * gx + blockIdx.x;
    const int q = nwg >> 3, r = nwg & 7;
    const int xcd = flat & 7, loc = flat >> 3;
    const int wg = (xcd < r ? xcd * (q + 1) : r * (q + 1) + (xcd - r) * q) + loc;
    const int bm = (wg / gx) * 128;
    const int bn = (wg % gx) * 128;

    const int lane = tid & 63;
    const int wid = tid >> 6;
    const int wr = wid >> 1, wc = wid & 1;

    f32x4 acc[4][4] = {};

    // staging: thread t -> row t>>2 (per 64-row half), stored chunk t&3.
    // global column chunk = (t&3) ^ ((t>>3)&3)  [inverse of stored swizzle]
    const int arow = tid >> 2;
    const int gcol = ((tid & 3) ^ ((tid >> 3) & 3)) * 8;
    const ushort* Ag0 = A + (size_t)(bm + arow) * K + gcol;
    const ushort* Ag1 = A + (size_t)(bm + 64 + arow) * K + gcol;
    const ushort* Bg0 = Bt + (size_t)(bn + arow) * K + gcol;
    const ushort* Bg1 = Bt + (size_t)(bn + 64 + arow) * K + gcol;
    const int wofs = (tid & ~63) * 8;   // wave-uniform LDS base, HW adds lane*16B

    const int fr = lane & 15;
    // read: logical chunk = lane>>4; stored = chunk ^ ((row>>1)&3), row%16==fr
    const int rchunk = ((lane >> 4) ^ ((fr >> 1) & 3)) * 8;

    const int NT = K >> 5;   // 4 or 8 (always >= 4 here)

    // prologue: stage tiles 0,1 (8 loads in flight)
    #pragma unroll
    for (int t = 0; t < 2; ++t) {
        const int k0 = t << 5;
        ushort* a = As[t]; ushort* b = Bs[t];
        gload_lds16(Ag0 + k0, a + wofs);
        gload_lds16(Ag1 + k0, a + 2048 + wofs);
        gload_lds16(Bg0 + k0, b + wofs);
        gload_lds16(Bg1 + k0, b + 2048 + wofs);
    }

    int sl = 0;
    for (int it = 0; it < NT; ++it) {
        if (it + 2 < NT) {                       // prefetch tile it+2 (depth-2)
            int wsl = sl + 2; if (wsl >= 3) wsl -= 3;
            const int k0 = (it + 2) << 5;
            ushort* a = As[wsl]; ushort* b = Bs[wsl];
            gload_lds16(Ag0 + k0, a + wofs);
            gload_lds16(Ag1 + k0, a + 2048 + wofs);
            gload_lds16(Bg0 + k0, b + wofs);
            gload_lds16(Bg1 + k0, b + 2048 + wofs);
            asm volatile("s_waitcnt vmcnt(8)" ::: "memory");   // tile it done; 2 tiles in flight
        } else if (it + 1 < NT) {
            asm volatile("s_waitcnt vmcnt(4)" ::: "memory");
        } else {
            asm volatile("s_waitcnt vmcnt(0)" ::: "memory");
        }
        SCHED_FENCE();
        RAW_BARRIER();                           // whole tile it resident (all waves)

        const ushort* as = As[sl];
        const ushort* bs = Bs[sl];
        short8 af[4], bf[4];
        #pragma unroll
        for (int m = 0; m < 4; ++m)
            af[m] = *(const short8*)&as[(wr * 64 + m * 16 + fr) * 32 + rchunk];
        #pragma unroll
        for (int n = 0; n < 4; ++n)
            bf[n] = *(const short8*)&bs[(wc * 64 + n * 16 + fr) * 32 + rchunk];
        __builtin_amdgcn_s_setprio(1);
        #pragma unroll
        for (int m = 0; m < 4; ++m)
            #pragma unroll
            for (int n = 0; n < 4; ++n)
                acc[m][n] = __builtin_amdgcn_mfma_f32_16x16x32_bf16(af[m], bf[n], acc[m][n], 0, 0, 0);
        __builtin_amdgcn_s_setprio(0);

        asm volatile("s_waitcnt lgkmcnt(0)" ::: "memory");     // reads of slot done
        SCHED_FENCE();
        RAW_BARRIER();                           // safe for next writer of this slot
        sl = sl + 1; if (sl >= 3) sl -= 3;
    }

    // epilogue: C/D layout col=lane&15, row=(lane>>4)*4+reg
    float s1[4], s2[4];
    if constexpr (MODE == 0) {
        #pragma unroll
        for (int n = 0; n < 4; ++n) { s1[n] = 0.f; s2[n] = 0.f; }
    }
    #pragma unroll
    for (int n = 0; n < 4; ++n) {
        const int col = bn + wc * 64 + n * 16 + fr;
        const float bv = bias[col];
        #pragma unroll
        for (int m = 0; m < 4; ++m) {
            const int row0 = bm + wr * 64 + m * 16 + (lane >> 4) * 4;
            #pragma unroll
            for (int rr = 0; rr < 4; ++rr) {
                float v = acc[m][n][rr] + bv;
                if constexpr (MODE == 1) {
                    v = fmaxf(v, 0.f);
                    ((ushort*)Cout)[(size_t)(row0 + rr) * ldc + col] = f32_to_bf16(v);
                } else {
                    ((float*)Cout)[(size_t)(row0 + rr) * ldc + col] = v;
                    if (row0 + rr < Nvalid) { s1[n] += v; s2[n] += v * v; }
                }
            }
        }
    }
    if constexpr (MODE == 0) {
        #pragma unroll
        for (int n = 0; n < 4; ++n) {
            float a = s1[n], b = s2[n];
            a += __shfl_xor(a, 16); b += __shfl_xor(b, 16);
            a += __shfl_xor(a, 32); b += __shfl_xor(b, 32);
            if ((lane >> 4) == 0) {
                int col = bn + wc * 64 + n * 16 + fr;
                atomicAdd(&extra[col], a);
                atomicAdd(&extra[256 + col], b);
            }
        }
    }
}

// ---------------- head GEMM: 256x128, BK=32, 8 waves, ring-3 depth-2 ---------
// T-tile = relu(Hcat[256x768] @ lin1t^T[128x768] + b); fused lin2 dot ->
// part[coltile][row][0..1].  Atomic-free global (LDS combine).

__global__ __launch_bounds__(512) void gemm_head(
    const ushort* __restrict__ A,    // Hcat [MP x 768]
    const ushort* __restrict__ Bt,   // lin1t [768 x 768]
    const float* __restrict__ bias,  // lin1_b [768]
    const float* __restrict__ w2,    // lin2_W [768 x 2]
    float* __restrict__ part,        // [6][MP][2]
    int K, int MP) {
    __shared__ ushort As[3][256 * 32];  // 48 KB
    __shared__ ushort Bs[3][128 * 32];  // 24 KB
    __shared__ float sm_part[256][2];   // 2 KB   -> 74 KB total, 2 blocks/CU
    const int tid = threadIdx.x;

    // XCD-bijective swizzle (nwg = 6*196 = 1176, %8==0)
    const int gx = gridDim.x;
    const int nwg = gx * gridDim.y;
    const int flat = blockIdx.y * gx + blockIdx.x;
    const int q = nwg >> 3, r = nwg & 7;
    const int xcd = flat & 7, loc = flat >> 3;
    const int wg = (xcd < r ? xcd * (q + 1) : r * (q + 1) + (xcd - r) * q) + loc;
    const int bm = (wg / gx) * 256;
    const int bn = (wg % gx) * 128;
    const int coltile = wg % gx;

    const int lane = tid & 63;
    const int wid = tid >> 6;        // 0..7
    const int wr = wid >> 1;         // 0..3 (64-row band of 256)
    const int wc = wid & 1;          // 0..1 (64-col half of 128)

    sm_part[tid >> 1][tid & 1] = 0.f;

    f32x4 acc[4][4] = {};

    // staging: thread t -> row t>>2 (0..127 per section), stored chunk t&3;
    // global column chunk = (t&3) ^ ((t>>3)&3)
    const int arow = tid >> 2;
    const int gcol = ((tid & 3) ^ ((tid >> 3) & 3)) * 8;
    const ushort* Ag0 = A + (size_t)(bm + arow) * K + gcol;         // rows 0..127
    const ushort* Ag1 = A + (size_t)(bm + 128 + arow) * K + gcol;   // rows 128..255
    const ushort* Bg0 = Bt + (size_t)(bn + arow) * K + gcol;        // 128 rows
    const int wofs = (tid & ~63) * 8;

    const int fr = lane & 15;
    const int rchunk = ((lane >> 4) ^ ((fr >> 1) & 3)) * 8;

    const int NT = K >> 5;   // 24

    // prologue: stage tiles 0,1 (6 loads in flight)
    #pragma unroll
    for (int t = 0; t < 2; ++t) {
        const int k0 = t << 5;
        ushort* a = As[t]; ushort* b = Bs[t];
        gload_lds16(Ag0 + k0, a + wofs);
        gload_lds16(Ag1 + k0, a + 4096 + wofs);
        gload_lds16(Bg0 + k0, b + wofs);
    }

    int sl = 0;
    for (int it = 0; it < NT; ++it) {
        if (it + 2 < NT) {                       // prefetch tile it+2 (depth-2)
            int wsl = sl + 2; if (wsl >= 3) wsl -= 3;
            const int k0 = (it + 2) << 5;
            ushort* a = As[wsl]; ushort* b = Bs[wsl];
            gload_lds16(Ag0 + k0, a + wofs);
            gload_lds16(Ag1 + k0, a + 4096 + wofs);
            gload_lds16(Bg0 + k0, b + wofs);
            asm volatile("s_waitcnt vmcnt(6)" ::: "memory");   // tile it done; 2 in flight
        } else if (it + 1 < NT) {
            asm volatile("s_waitcnt vmcnt(3)" ::: "memory");
        } else {
            asm volatile("s_waitcnt vmcnt(0)" ::: "memory");
        }
        SCHED_FENCE();
        RAW_BARRIER();

        const ushort* as = As[sl];
        const ushort* bs = Bs[sl];
        short8 af[4], bf[4];
        #pragma unroll
        for (int m = 0; m < 4; ++m)
            af[m] = *(const short8*)&as[(wr * 64 + m * 16 + fr) * 32 + rchunk];
        #pragma unroll
        for (int n = 0; n < 4; ++n)
            bf[n] = *(const short8*)&bs[(wc * 64 + n * 16 + fr) * 32 + rchunk];
        __builtin_amdgcn_s_setprio(1);
        #pragma unroll
        for (int m = 0; m < 4; ++m)
            #pragma unroll
            for (int n = 0; n < 4; ++n)
                acc[m][n] = __builtin_amdgcn_mfma_f32_16x16x32_bf16(af[m], bf[n], acc[m][n], 0, 0, 0);
        __builtin_amdgcn_s_setprio(0);

        asm volatile("s_waitcnt lgkmcnt(0)" ::: "memory");
        SCHED_FENCE();
        RAW_BARRIER();
        sl = sl + 1; if (sl >= 3) sl -= 3;
    }

    // epilogue: relu(v+bias) dot w2 -> reduce over fr -> LDS combine
    #pragma unroll
    for (int m = 0; m < 4; ++m) {
        #pragma unroll
        for (int rr = 0; rr < 4; ++rr) {
            float o0 = 0.f, o1 = 0.f;
            #pragma unroll
            for (int n = 0; n < 4; ++n) {
                int col = bn + wc * 64 + n * 16 + fr;
                float v = fmaxf(acc[m][n][rr] + bias[col], 0.f);
                o0 = fmaf(v, w2[col * 2 + 0], o0);
                o1 = fmaf(v, w2[col * 2 + 1], o1);
            }
            o0 += __shfl_xor(o0, 1); o1 += __shfl_xor(o1, 1);
            o0 += __shfl_xor(o0, 2); o1 += __shfl_xor(o1, 2);
            o0 += __shfl_xor(o0, 4); o1 += __shfl_xor(o1, 4);
            o0 += __shfl_xor(o0, 8); o1 += __shfl_xor(o1, 8);
            if (fr == 0) {
                int lrow = wr * 64 + m * 16 + (lane >> 4) * 4 + rr;
                atomicAdd(&sm_part[lrow][0], o0);
                atomicAdd(&sm_part[lrow][1], o1);
            }
        }
    }
    __syncthreads();
    {
        int lrow = tid >> 1, comp = tid & 1;
        part[((size_t)coltile * MP + bm + lrow) * 2 + comp] = sm_part[lrow][comp];
    }
}

// ---------------- BN apply (normalize + relu, write bf16) ----------------

__global__ void bn_apply(const float* __restrict__ h, const float* __restrict__ sums,
                         const float* __restrict__ g, const float* __restrict__ be,
                         ushort* __restrict__ outb, int Nrows) {
    int total = Nrows * 128;
    float inv = 1.0f / (float)Nrows;
    for (int idx = blockIdx.x * blockDim.x + threadIdx.x; idx < total;
         idx += gridDim.x * blockDim.x) {
        int row = idx >> 7;
        int cp = (idx & 127) * 2;
        float2 v = *(const float2*)(h + (size_t)row * 256 + cp);
        float mu0 = sums[cp] * inv,     mu1 = sums[cp + 1] * inv;
        float va0 = sums[256 + cp] * inv - mu0 * mu0;
        float va1 = sums[257 + cp] * inv - mu1 * mu1;
        float o0 = fmaxf((v.x - mu0) * rsqrtf(va0 + 1e-5f) * g[cp]     + be[cp],     0.f);
        float o1 = fmaxf((v.y - mu1) * rsqrtf(va1 + 1e-5f) * g[cp + 1] + be[cp + 1], 0.f);
        *(uint*)(outb + (size_t)row * 256 + cp) = pack_bf16(o0, o1);
    }
}

// ---------------- finalize: sum 6 partials + bias + softmax ----------------

__global__ void finalize6(const float* __restrict__ part, const float* __restrict__ b2,
                          float* __restrict__ out, int Nrows, int MP) {
    int i = blockIdx.x * blockDim.x + threadIdx.x;
    if (i >= Nrows) return;
    float h0 = b2[0], h1 = b2[1];
    #pragma unroll
    for (int c = 0; c < 6; ++c) {
        h0 += part[((size_t)c * MP + i) * 2 + 0];
        h1 += part[((size_t)c * MP + i) * 2 + 1];
    }
    out[2 * i] = h0;
    out[2 * i + 1] = h1;
    float m = fmaxf(h0, h1);
    float e0 = expf(h0 - m), e1 = expf(h1 - m);
    float s = e0 + e1;
    out[(size_t)2 * Nrows + 2 * i] = e0 / s;
    out[(size_t)2 * Nrows + 2 * i + 1] = e1 / s;
}

// ---------------------------------------------------------------------------

extern "C" void kernel_launch(void* const* d_in, const int* in_sizes, int n_in,
                              void* d_out, int out_size, void* d_ws, size_t ws_size,
                              hipStream_t stream) {
    const int N = in_sizes[0] / GIN_N_FEAT_IN;     // 50000
    const int E = in_sizes[1] / 2;                 // 800000
    const int MP = M_PAD_ROWS;
    const int nchunks = (N + 255) / 256;           // 196

    const float* x  = (const float*)d_in[0];
    const int*   ei = (const int*)d_in[1];
    const float* cW1[3] = {(const float*)d_in[2],  (const float*)d_in[8],  (const float*)d_in[14]};
    const float* cb1[3] = {(const float*)d_in[3],  (const float*)d_in[9],  (const float*)d_in[15]};
    const float* cg [3] = {(const float*)d_in[4],  (const float*)d_in[10], (const float*)d_in[16]};
    const float* cbe[3] = {(const float*)d_in[5],  (const float*)d_in[11], (const float*)d_in[17]};
    const float* cW2[3] = {(const float*)d_in[6],  (const float*)d_in[12], (const float*)d_in[18]};
    const float* cb2[3] = {(const float*)d_in[7],  (const float*)d_in[13], (const float*)d_in[19]};
    const float* lin1_W = (const float*)d_in[20];  // [768,768]
    const float* lin1_b = (const float*)d_in[21];
    const float* lin2_W = (const float*)d_in[22];  // [768,2]
    const float* lin2_b = (const float*)d_in[23];
    float* out = (float*)d_out;

    // ---- workspace carve-up (row buffers padded to MP rows) ----
    char* ws = (char*)d_ws;
    size_t off = 0;
    auto carve = [&](size_t bytes) {
        void* p = ws + off;
        off += (bytes + 255) & ~(size_t)255;
        return p;
    };
    ushort* Hcat   = (ushort*)carve((size_t)MP * 768 * 2);   // bf16 h1|h2|h3
    float*  hlin   = (float*) carve((size_t)MP * 256 * 4);   // f32 gemm1 out
    ushort* hlin_b = (ushort*)carve((size_t)MP * 256 * 2);   // bf16 after BN
    ushort* hpre   = (ushort*)carve((size_t)MP * 256 * 2);   // bf16 agg out
    ushort* xb     = (ushort*)carve((size_t)MP * 128 * 2);   // bf16 input
    ushort* w1t[3] = {(ushort*)carve(256 * 256 * 2), (ushort*)carve(256 * 256 * 2),
                      (ushort*)carve(256 * 256 * 2)};
    ushort* w2t[3] = {(ushort*)carve(256 * 256 * 2), (ushort*)carve(256 * 256 * 2),
                      (ushort*)carve(256 * 256 * 2)};
    ushort* lin1t  = (ushort*)carve((size_t)768 * 768 * 2);
    int*   row_st  = (int*)carve((size_t)(N + 1) * 4);
    int*   cursor  = (int*)carve((size_t)N * 4);
    int*   perm    = (int*)carve((size_t)E * 4);
    int*   csums   = (int*)carve(256 * 4);
    float* bnsums  = (float*)carve(512 * 4);
    float* part    = (float*)carve((size_t)6 * MP * 2 * 4);
    (void)ws_size;

    // ---- conversions ----
    cvt_f32_bf16<<<1024, 256, 0, stream>>>(x, xb, N * 64);
    WPrep wp;
    wp.src[0] = cW1[0]; wp.dst[0] = w1t[0]; wp.R[0] = 128; wp.C[0] = 256;
    wp.src[1] = cW1[1]; wp.dst[1] = w1t[1]; wp.R[1] = 256; wp.C[1] = 256;
    wp.src[2] = cW1[2]; wp.dst[2] = w1t[2]; wp.R[2] = 256; wp.C[2] = 256;
    wp.src[3] = cW2[0]; wp.dst[3] = w2t[0]; wp.R[3] = 256; wp.C[3] = 256;
    wp.src[4] = cW2[1]; wp.dst[4] = w2t[1]; wp.R[4] = 256; wp.C[4] = 256;
    wp.src[5] = cW2[2]; wp.dst[5] = w2t[2]; wp.R[5] = 256; wp.C[5] = 256;
    wp.src[6] = lin1_W; wp.dst[6] = lin1t;  wp.R[6] = 768; wp.C[6] = 768;
    prep_weights<<<dim3(576, 7), 256, 0, stream>>>(wp);

    // ---- CSR build (3-stage parallel scan) ----
    hipMemsetAsync(cursor, 0, (size_t)N * 4, stream);
    count_kernel<<<1024, 256, 0, stream>>>(ei, cursor, E);
    scan_chunk<<<nchunks, 256, 0, stream>>>(cursor, row_st, csums, N);
    scan_tops<<<1, 256, 0, stream>>>(csums, row_st, nchunks, N, E);
    scan_add<<<nchunks, 256, 0, stream>>>(row_st, cursor, csums, N);
    scatter_kernel<<<1024, 256, 0, stream>>>(ei, cursor, perm, E);

    const dim3 ggrid(2, MP / 128);       // conv GEMMs (784 WGs, %8==0)
    const int aggblocks = (N + 3) / 4;   // wave per node

    // ---- 3 GIN conv layers ----
    for (int L = 0; L < 3; ++L) {
        if (L == 0)
            agg2<128><<<aggblocks, 256, 0, stream>>>(xb, 128, row_st, perm, hpre, N);
        else
            agg2<256><<<aggblocks, 256, 0, stream>>>(Hcat + (size_t)(L - 1) * 256, 768,
                                                     row_st, perm, hpre, N);

        // GEMM1 + fused BN stats
        hipMemsetAsync(bnsums, 0, 512 * 4, stream);
        gemm_mfma<0><<<ggrid, 256, 0, stream>>>(
            hpre, w1t[L], cb1[L], hlin, 256, (L == 0) ? 128 : 256, bnsums, N);

        bn_apply<<<2048, 256, 0, stream>>>(hlin, bnsums, cg[L], cbe[L], hlin_b, N);

        // GEMM2 -> Hcat column block L (bf16, ldc=768)
        gemm_mfma<1><<<ggrid, 256, 0, stream>>>(
            hlin_b, w2t[L], cb2[L], (void*)(Hcat + (size_t)L * 256), 768, 256,
            nullptr, 0);
    }

    // ---- head: 256x128-tile fused gemm (lin1+relu+lin2 partials) ----
    gemm_head<<<dim3(6, MP / 256), 512, 0, stream>>>(
        Hcat, lin1t, lin1_b, lin2_W, part, 768, MP);

    finalize6<<<(N + 255) / 256, 256, 0, stream>>>(part, lin2_b, out, N, MP);
}